// Round 5
// baseline (5206.994 us; speedup 1.0000x reference)
//
#include <hip/hip_runtime.h>

#define D 64
#define AB_SHIFT 8
#define AROWS 256                 // rows per accumulator bucket
#define NAB_MAX 1280              // >= 1172 buckets
#define EPB 8192                  // edges per hist/partition block
#define SPMM_T 512                // 8 waves

// ---------- bucket histogram ----------
__global__ __launch_bounds__(256) void bucket_hist(
    const int* __restrict__ rows, int* __restrict__ cnt, int nedges, int nab)
{
    __shared__ int h[NAB_MAX];
    int t = threadIdx.x;
    for (int i = t; i < nab; i += 256) h[i] = 0;
    __syncthreads();
    int base = blockIdx.x * EPB;
    #pragma unroll
    for (int i = 0; i < EPB / 256; i++) {
        int e = base + i * 256 + t;
        if (e < nedges) atomicAdd(&h[rows[e] >> AB_SHIFT], 1);
    }
    __syncthreads();
    for (int i = t; i < nab; i += 256) if (h[i]) atomicAdd(&cnt[i], h[i]);
}

// ---------- exclusive scan of bucket counts (single block) ----------
__global__ __launch_bounds__(1024) void scan_buckets(
    const int* __restrict__ cnt, int* __restrict__ bptr, int* __restrict__ gcur,
    int nab, int nedges)
{
    __shared__ int lds[1024];
    int t = threadIdx.x;
    int i0 = 2 * t, i1 = 2 * t + 1;
    int a = (i0 < nab) ? cnt[i0] : 0;
    int b = (i1 < nab) ? cnt[i1] : 0;
    int s = a + b;
    lds[t] = s;
    __syncthreads();
    for (int ofs = 1; ofs < 1024; ofs <<= 1) {
        int x = (t >= ofs) ? lds[t - ofs] : 0;
        __syncthreads();
        lds[t] += x;
        __syncthreads();
    }
    int excl = lds[t] - s;
    if (i0 < nab) { bptr[i0] = excl;     gcur[i0] = excl; }
    if (i1 < nab) { bptr[i1] = excl + a; gcur[i1] = excl + a; }
    if (t == 0) bptr[nab] = nedges;
}

// ---------- partition: two-sweep LDS-cursor bin into bucket segments ----------
__global__ __launch_bounds__(256) void partition_edges(
    const int* __restrict__ rows, const int* __restrict__ cols,
    const float* __restrict__ vals, int* __restrict__ gcur,
    int2* __restrict__ staged, int nedges, int nab)
{
    __shared__ int h[NAB_MAX];
    __shared__ int cur[NAB_MAX];
    int t = threadIdx.x;
    for (int i = t; i < nab; i += 256) h[i] = 0;
    __syncthreads();
    int base = blockIdx.x * EPB;
    #pragma unroll
    for (int i = 0; i < EPB / 256; i++) {
        int e = base + i * 256 + t;
        if (e < nedges) atomicAdd(&h[rows[e] >> AB_SHIFT], 1);
    }
    __syncthreads();
    for (int i = t; i < nab; i += 256) {
        int c = h[i];
        cur[i] = c ? atomicAdd(&gcur[i], c) : 0;
    }
    __syncthreads();
    #pragma unroll
    for (int i = 0; i < EPB / 256; i++) {
        int e = base + i * 256 + t;
        if (e < nedges) {
            int r = rows[e];
            int pos = atomicAdd(&cur[r >> AB_SHIFT], 1);
            staged[pos] = make_int2(((r & (AROWS - 1)) << 19) | cols[e],
                                    __float_as_int(vals[e]));
        }
    }
}

// ---------- LDS-accumulator bucket spmm ----------
// One block per 256-row bucket. acc in LDS; edges streamed; writeout coalesced.
// FUSED: out[row] = acc + e0[row] + out[row](e1) + e2buf[row](e2)
template <bool FUSED>
__global__ __launch_bounds__(SPMM_T) void spmm_bucket(
    const int* __restrict__ bptr, const int2* __restrict__ staged,
    const float* __restrict__ srcA, const float* __restrict__ srcB, int split,
    const float* __restrict__ u, const float* __restrict__ it, int user,
    const float* __restrict__ e2buf, float* __restrict__ out, int n)
{
    __shared__ float acc[AROWS * D];   // 64 KB
    int t = threadIdx.x;
    int b = blockIdx.x;
    for (int i = t; i < AROWS * D; i += SPMM_T) acc[i] = 0.f;
    __syncthreads();

    int seg0 = bptr[b], seg1 = bptr[b + 1];
    int len  = seg1 - seg0;
    int lane = t & 63;
    int wave = t >> 6;                 // 0..7
    int w0 = seg0 + (int)((long long)len * wave / 8);
    int w1 = seg0 + (int)((long long)len * (wave + 1) / 8);

    int e = w0;
    for (; e + 8 <= w1; e += 8) {
        int2 r[8];
        float xv[8];
        #pragma unroll
        for (int j = 0; j < 8; j++) r[j] = staged[e + j];
        #pragma unroll
        for (int j = 0; j < 8; j++) {
            int col = r[j].x & 0x7FFFF;
            const float* src = (col < split) ? srcA + (size_t)col * D
                                             : srcB + (size_t)(col - split) * D;
            xv[j] = src[lane];
        }
        #pragma unroll
        for (int j = 0; j < 8; j++) {
            int rl = (unsigned)r[j].x >> 19;
            float v = __int_as_float(r[j].y);
            atomicAdd(&acc[rl * D + lane], v * xv[j]);
        }
    }
    for (; e < w1; ++e) {
        int2 r = staged[e];
        int col = r.x & 0x7FFFF;
        const float* src = (col < split) ? srcA + (size_t)col * D
                                         : srcB + (size_t)(col - split) * D;
        float xv = src[lane];
        int rl = (unsigned)r.x >> 19;
        atomicAdd(&acc[rl * D + lane], __int_as_float(r.y) * xv);
    }
    __syncthreads();

    // writeout: AROWS*D floats = 4096 float4
    int rowbase = b << AB_SHIFT;
    for (int i = t; i < AROWS * D / 4; i += SPMM_T) {
        int row = rowbase + (i >> 4);
        if (row >= n) break;
        float4 a = *(const float4*)&acc[i * 4];
        size_t off = (size_t)rowbase * D + (size_t)i * 4;
        if (FUSED) {
            int fo = (i & 15) * 4;
            const float* e0 = (row < user) ? u + (size_t)row * D
                                           : it + (size_t)(row - user) * D;
            float4 b0 = *(const float4*)(e0 + fo);
            float4 b1 = *(const float4*)(out + off);     // e1
            float4 b2 = *(const float4*)(e2buf + off);   // e2
            a.x += b0.x + b1.x + b2.x;
            a.y += b0.y + b1.y + b2.y;
            a.z += b0.z + b1.z + b2.z;
            a.w += b0.w + b1.w + b2.w;
        }
        *(float4*)(out + off) = a;
    }
}

// ---------- launch ----------
static inline size_t alignup(size_t x) { return (x + 255) & ~(size_t)255; }

extern "C" void kernel_launch(void* const* d_in, const int* in_sizes, int n_in,
                              void* d_out, int out_size, void* d_ws, size_t ws_size,
                              hipStream_t stream) {
    const int*   rows = (const int*)  d_in[0];
    const int*   cols = (const int*)  d_in[1];
    const float* vals = (const float*)d_in[2];
    const float* u    = (const float*)d_in[3];
    const float* it   = (const float*)d_in[4];

    const int nedges = in_sizes[0];
    const int user   = in_sizes[3] / D;
    const int item   = in_sizes[4] / D;
    const int n      = user + item;
    const int nab    = (n + AROWS - 1) >> AB_SHIFT;   // 1172

    float* out = (float*)d_out;

    // workspace carve
    char* w = (char*)d_ws;
    int*  cnt  = (int*)w;  w += alignup((size_t)nab * sizeof(int));
    int*  bptr = (int*)w;  w += alignup((size_t)(nab + 1) * sizeof(int));
    int*  gcur = (int*)w;  w += alignup((size_t)nab * sizeof(int));
    int2* staged = (int2*)w; w += alignup((size_t)nedges * sizeof(int2));
    float* buf2 = (float*)w;                 // n * D floats

    const int hblocks = (nedges + EPB - 1) / EPB;

    hipMemsetAsync(cnt, 0, (size_t)nab * sizeof(int), stream);
    bucket_hist<<<hblocks, 256, 0, stream>>>(rows, cnt, nedges, nab);
    scan_buckets<<<1, 1024, 0, stream>>>(cnt, bptr, gcur, nab, nedges);
    partition_edges<<<hblocks, 256, 0, stream>>>(rows, cols, vals, gcur, staged, nedges, nab);

    // out = e1 = spmm(e0)
    spmm_bucket<false><<<nab, SPMM_T, 0, stream>>>(
        bptr, staged, u, it, user, nullptr, nullptr, user, nullptr, out, n);
    // buf2 = e2 = spmm(e1)
    spmm_bucket<false><<<nab, SPMM_T, 0, stream>>>(
        bptr, staged, out, out + (size_t)user * D, user, nullptr, nullptr, user, nullptr, buf2, n);
    // out = e0 + e1 + e2 + spmm(e2)
    spmm_bucket<true><<<nab, SPMM_T, 0, stream>>>(
        bptr, staged, buf2, buf2 + (size_t)user * D, user, u, it, user, buf2, out, n);
}

// Round 6
// 756.772 us; speedup vs baseline: 6.8805x; 6.8805x over previous
//
#include <hip/hip_runtime.h>

#define D 64
#define AB_SHIFT 8
#define AROWS 256                 // rows per bucket
#define NAB_MAX 1280              // >= 1172 buckets
#define EPB 8192                  // edges per hist/partition block
#define SORT_T 512
#define SORT_CAP 8064             // LDS record capacity (63 KB)

// ---------- bucket histogram ----------
__global__ __launch_bounds__(256) void bucket_hist(
    const int* __restrict__ rows, int* __restrict__ cnt, int nedges, int nab)
{
    __shared__ int h[NAB_MAX];
    int t = threadIdx.x;
    for (int i = t; i < nab; i += 256) h[i] = 0;
    __syncthreads();
    int base = blockIdx.x * EPB;
    #pragma unroll
    for (int i = 0; i < EPB / 256; i++) {
        int e = base + i * 256 + t;
        if (e < nedges) atomicAdd(&h[rows[e] >> AB_SHIFT], 1);
    }
    __syncthreads();
    for (int i = t; i < nab; i += 256) if (h[i]) atomicAdd(&cnt[i], h[i]);
}

// ---------- exclusive scan of bucket counts (single block, nab <= 2048) ----------
__global__ __launch_bounds__(1024) void scan_buckets(
    const int* __restrict__ cnt, int* __restrict__ bptr, int* __restrict__ gcur,
    int nab, int nedges)
{
    __shared__ int lds[1024];
    int t = threadIdx.x;
    int i0 = 2 * t, i1 = 2 * t + 1;
    int a = (i0 < nab) ? cnt[i0] : 0;
    int b = (i1 < nab) ? cnt[i1] : 0;
    int s = a + b;
    lds[t] = s;
    __syncthreads();
    for (int ofs = 1; ofs < 1024; ofs <<= 1) {
        int x = (t >= ofs) ? lds[t - ofs] : 0;
        __syncthreads();
        lds[t] += x;
        __syncthreads();
    }
    int excl = lds[t] - s;
    if (i0 < nab) { bptr[i0] = excl;     gcur[i0] = excl; }
    if (i1 < nab) { bptr[i1] = excl + a; gcur[i1] = excl + a; }
    if (t == 0) bptr[nab] = nedges;
}

// ---------- partition: two-sweep LDS-cursor bin into bucket segments ----------
__global__ __launch_bounds__(256) void partition_edges(
    const int* __restrict__ rows, const int* __restrict__ cols,
    const float* __restrict__ vals, int* __restrict__ gcur,
    int2* __restrict__ staged, int nedges, int nab)
{
    __shared__ int h[NAB_MAX];
    __shared__ int cur[NAB_MAX];
    int t = threadIdx.x;
    for (int i = t; i < nab; i += 256) h[i] = 0;
    __syncthreads();
    int base = blockIdx.x * EPB;
    #pragma unroll
    for (int i = 0; i < EPB / 256; i++) {
        int e = base + i * 256 + t;
        if (e < nedges) atomicAdd(&h[rows[e] >> AB_SHIFT], 1);
    }
    __syncthreads();
    for (int i = t; i < nab; i += 256) {
        int c = h[i];
        cur[i] = c ? atomicAdd(&gcur[i], c) : 0;
    }
    __syncthreads();
    #pragma unroll
    for (int i = 0; i < EPB / 256; i++) {
        int e = base + i * 256 + t;
        if (e < nedges) {
            int r = rows[e];
            int pos = atomicAdd(&cur[r >> AB_SHIFT], 1);
            staged[pos] = make_int2(((r & (AROWS - 1)) << 19) | cols[e],
                                    __float_as_int(vals[e]));
        }
    }
}

// ---------- in-LDS row sort of each bucket segment ----------
// One block per bucket: hist 256 rows, LDS scan, scatter records row-ordered
// into LDS, dump sequentially to pairs[]. endp[row] written coalesced.
__global__ __launch_bounds__(SORT_T) void bucket_sort(
    const int* __restrict__ bptr, const int2* __restrict__ staged,
    int2* __restrict__ pairs, int* __restrict__ endp, int n)
{
    __shared__ int cnt[AROWS];
    __shared__ int pfx[AROWS];
    __shared__ int2 buf[SORT_CAP];
    int t = threadIdx.x;
    int b = blockIdx.x;
    int seg0 = bptr[b], seg1 = bptr[b + 1];
    int len = seg1 - seg0;
    if (t < AROWS) cnt[t] = 0;
    __syncthreads();
    // pass 1: per-row histogram
    for (int i = t; i < len; i += SORT_T) {
        int rl = (unsigned)staged[seg0 + i].x >> 19;
        atomicAdd(&cnt[rl], 1);
    }
    __syncthreads();
    if (t < AROWS) pfx[t] = cnt[t];
    __syncthreads();
    for (int ofs = 1; ofs < AROWS; ofs <<= 1) {
        int x = (t >= ofs && t < AROWS) ? pfx[t - ofs] : 0;
        __syncthreads();
        if (t < AROWS) pfx[t] += x;       // inclusive prefix
        __syncthreads();
    }
    int rowbase = b << AB_SHIFT;
    if (t < AROWS && rowbase + t < n) endp[rowbase + t] = seg0 + pfx[t];
    __syncthreads();
    if (t < AROWS) cnt[t] = pfx[t] - cnt[t];   // running cursor (exclusive)
    __syncthreads();
    // pass 2: scatter into LDS in row order (spill to global if > CAP; never in practice)
    for (int i = t; i < len; i += SORT_T) {
        int2 p = staged[seg0 + i];
        int rl = (unsigned)p.x >> 19;
        int pos = atomicAdd(&cnt[rl], 1);
        int2 rec = make_int2(p.x & 0x7FFFF, p.y);
        if (pos < SORT_CAP) buf[pos] = rec;
        else pairs[seg0 + pos] = rec;
    }
    __syncthreads();
    // dump: fully coalesced sequential write
    int m = len < SORT_CAP ? len : SORT_CAP;
    for (int i = t; i < m; i += SORT_T) pairs[seg0 + i] = buf[i];
}

// ---------- gather-style CSR spmm (register accumulation, 2-deep pipeline) ----------
template <bool FUSED>
__global__ __launch_bounds__(256) void spmm_csr(
    const int* __restrict__ endp, const int2* __restrict__ pairs,
    const float* __restrict__ srcA, const float* __restrict__ srcB, int split,
    const float* __restrict__ u, const float* __restrict__ it, int user,
    const float* __restrict__ prev, float* __restrict__ out, int n)
{
    int row = blockIdx.x * 16 + (threadIdx.x >> 4);
    if (row >= n) return;
    int l = threadIdx.x & 15;
    int start = row ? endp[row - 1] : 0;
    int end = endp[row];
    float ax = 0.f, ay = 0.f, az = 0.f, aw = 0.f;
    int e = start;
    for (; e + 2 <= end; e += 2) {
        int2 p0 = pairs[e];
        int2 p1 = pairs[e + 1];
        int c0 = p0.x, c1 = p1.x;
        const float* s0 = (c0 < split) ? srcA + (size_t)c0 * D
                                       : srcB + (size_t)(c0 - split) * D;
        const float* s1 = (c1 < split) ? srcA + (size_t)c1 * D
                                       : srcB + (size_t)(c1 - split) * D;
        float4 x0 = *(const float4*)(s0 + l * 4);
        float4 x1 = *(const float4*)(s1 + l * 4);
        float v0 = __int_as_float(p0.y), v1 = __int_as_float(p1.y);
        ax = fmaf(v0, x0.x, ax); ay = fmaf(v0, x0.y, ay);
        az = fmaf(v0, x0.z, az); aw = fmaf(v0, x0.w, aw);
        ax = fmaf(v1, x1.x, ax); ay = fmaf(v1, x1.y, ay);
        az = fmaf(v1, x1.z, az); aw = fmaf(v1, x1.w, aw);
    }
    if (e < end) {
        int2 p = pairs[e];
        int col = p.x;
        float v = __int_as_float(p.y);
        const float* src = (col < split) ? srcA + (size_t)col * D
                                         : srcB + (size_t)(col - split) * D;
        float4 x = *(const float4*)(src + l * 4);
        ax = fmaf(v, x.x, ax); ay = fmaf(v, x.y, ay);
        az = fmaf(v, x.z, az); aw = fmaf(v, x.w, aw);
    }
    float* o = out + (size_t)row * D + l * 4;
    if (FUSED) {
        const float* e0 = (row < user) ? u + (size_t)row * D
                                       : it + (size_t)(row - user) * D;
        float4 b0 = *(const float4*)(e0 + l * 4);
        float4 b1 = *(const float4*)o;                                // e1
        float4 b2 = *(const float4*)(prev + (size_t)row * D + l * 4); // e2
        ax += b0.x + b1.x + b2.x;
        ay += b0.y + b1.y + b2.y;
        az += b0.z + b1.z + b2.z;
        aw += b0.w + b1.w + b2.w;
    }
    *(float4*)o = make_float4(ax, ay, az, aw);
}

// ---------- launch ----------
static inline size_t alignup(size_t x) { return (x + 255) & ~(size_t)255; }

extern "C" void kernel_launch(void* const* d_in, const int* in_sizes, int n_in,
                              void* d_out, int out_size, void* d_ws, size_t ws_size,
                              hipStream_t stream) {
    const int*   rows = (const int*)  d_in[0];
    const int*   cols = (const int*)  d_in[1];
    const float* vals = (const float*)d_in[2];
    const float* u    = (const float*)d_in[3];
    const float* it   = (const float*)d_in[4];

    const int nedges = in_sizes[0];
    const int user   = in_sizes[3] / D;
    const int item   = in_sizes[4] / D;
    const int n      = user + item;
    const int nab    = (n + AROWS - 1) >> AB_SHIFT;   // 1172

    float* out = (float*)d_out;

    // workspace carve
    char* w = (char*)d_ws;
    int*  cnt  = (int*)w;  w += alignup((size_t)nab * sizeof(int));
    int*  bptr = (int*)w;  w += alignup((size_t)(nab + 1) * sizeof(int));
    int*  gcur = (int*)w;  w += alignup((size_t)nab * sizeof(int));
    int*  endp = (int*)w;  w += alignup((size_t)n * sizeof(int));
    int2* pairs = (int2*)w; w += alignup((size_t)nedges * sizeof(int2));
    // staged (E*8 B) overlaps buf2 (n*D*4 B): staged dead after bucket_sort,
    // buf2 first written in spmm pass 2.
    int2*  staged = (int2*)w;
    float* buf2   = (float*)w;

    const int hblocks = (nedges + EPB - 1) / EPB;
    const int sblocks = (n + 15) / 16;

    hipMemsetAsync(cnt, 0, (size_t)nab * sizeof(int), stream);
    bucket_hist<<<hblocks, 256, 0, stream>>>(rows, cnt, nedges, nab);
    scan_buckets<<<1, 1024, 0, stream>>>(cnt, bptr, gcur, nab, nedges);
    partition_edges<<<hblocks, 256, 0, stream>>>(rows, cols, vals, gcur, staged, nedges, nab);
    bucket_sort<<<nab, SORT_T, 0, stream>>>(bptr, staged, pairs, endp, n);

    // out = e1 = spmm(e0)
    spmm_csr<false><<<sblocks, 256, 0, stream>>>(
        endp, pairs, u, it, user, nullptr, nullptr, user, nullptr, out, n);
    // buf2 = e2 = spmm(e1)
    spmm_csr<false><<<sblocks, 256, 0, stream>>>(
        endp, pairs, out, out + (size_t)user * D, user, nullptr, nullptr, user, nullptr, buf2, n);
    // out = e0 + e1 + e2 + spmm(e2)
    spmm_csr<true><<<sblocks, 256, 0, stream>>>(
        endp, pairs, buf2, buf2 + (size_t)user * D, user, u, it, user, buf2, out, n);
}

// Round 7
// 578.320 us; speedup vs baseline: 9.0037x; 1.3086x over previous
//
#include <hip/hip_runtime.h>

#define D 64
#define AB_SHIFT 8
#define AROWS 256                 // rows per bucket
#define NAB_MAX 1280              // >= 1172 buckets
#define EPB 8192                  // edges per hist/partition block
#define SORT_T 512
#define SORT_CAP 8064             // LDS record capacity (63 KB)

__device__ __forceinline__ unsigned short f2bf(float f) {
    unsigned u = __float_as_uint(f);
    return (unsigned short)((u + 0x7FFFu + ((u >> 16) & 1u)) >> 16);  // RNE
}
__device__ __forceinline__ float bf2f(unsigned short b) {
    return __uint_as_float(((unsigned)b) << 16);
}

// ---------- bucket histogram ----------
__global__ __launch_bounds__(256) void bucket_hist(
    const int* __restrict__ rows, int* __restrict__ cnt, int nedges, int nab)
{
    __shared__ int h[NAB_MAX];
    int t = threadIdx.x;
    for (int i = t; i < nab; i += 256) h[i] = 0;
    __syncthreads();
    int base = blockIdx.x * EPB;
    #pragma unroll
    for (int i = 0; i < EPB / 256; i++) {
        int e = base + i * 256 + t;
        if (e < nedges) atomicAdd(&h[rows[e] >> AB_SHIFT], 1);
    }
    __syncthreads();
    for (int i = t; i < nab; i += 256) if (h[i]) atomicAdd(&cnt[i], h[i]);
}

// ---------- exclusive scan of bucket counts (single block, nab <= 2048) ----------
__global__ __launch_bounds__(1024) void scan_buckets(
    const int* __restrict__ cnt, int* __restrict__ bptr, int* __restrict__ gcur,
    int nab, int nedges)
{
    __shared__ int lds[1024];
    int t = threadIdx.x;
    int i0 = 2 * t, i1 = 2 * t + 1;
    int a = (i0 < nab) ? cnt[i0] : 0;
    int b = (i1 < nab) ? cnt[i1] : 0;
    int s = a + b;
    lds[t] = s;
    __syncthreads();
    for (int ofs = 1; ofs < 1024; ofs <<= 1) {
        int x = (t >= ofs) ? lds[t - ofs] : 0;
        __syncthreads();
        lds[t] += x;
        __syncthreads();
    }
    int excl = lds[t] - s;
    if (i0 < nab) { bptr[i0] = excl;     gcur[i0] = excl; }
    if (i1 < nab) { bptr[i1] = excl + a; gcur[i1] = excl + a; }
    if (t == 0) bptr[nab] = nedges;
}

// ---------- partition: two-sweep LDS-cursor bin into bucket segments ----------
__global__ __launch_bounds__(256) void partition_edges(
    const int* __restrict__ rows, const int* __restrict__ cols,
    const float* __restrict__ vals, int* __restrict__ gcur,
    int2* __restrict__ staged, int nedges, int nab)
{
    __shared__ int h[NAB_MAX];
    __shared__ int cur[NAB_MAX];
    int t = threadIdx.x;
    for (int i = t; i < nab; i += 256) h[i] = 0;
    __syncthreads();
    int base = blockIdx.x * EPB;
    #pragma unroll
    for (int i = 0; i < EPB / 256; i++) {
        int e = base + i * 256 + t;
        if (e < nedges) atomicAdd(&h[rows[e] >> AB_SHIFT], 1);
    }
    __syncthreads();
    for (int i = t; i < nab; i += 256) {
        int c = h[i];
        cur[i] = c ? atomicAdd(&gcur[i], c) : 0;
    }
    __syncthreads();
    #pragma unroll
    for (int i = 0; i < EPB / 256; i++) {
        int e = base + i * 256 + t;
        if (e < nedges) {
            int r = rows[e];
            int pos = atomicAdd(&cur[r >> AB_SHIFT], 1);
            staged[pos] = make_int2(((r & (AROWS - 1)) << 19) | cols[e],
                                    __float_as_int(vals[e]));
        }
    }
}

// ---------- in-LDS row sort of each bucket segment ----------
__global__ __launch_bounds__(SORT_T) void bucket_sort(
    const int* __restrict__ bptr, const int2* __restrict__ staged,
    int2* __restrict__ pairs, int* __restrict__ endp, int n)
{
    __shared__ int cnt[AROWS];
    __shared__ int pfx[AROWS];
    __shared__ int2 buf[SORT_CAP];
    int t = threadIdx.x;
    int b = blockIdx.x;
    int seg0 = bptr[b], seg1 = bptr[b + 1];
    int len = seg1 - seg0;
    if (t < AROWS) cnt[t] = 0;
    __syncthreads();
    for (int i = t; i < len; i += SORT_T) {
        int rl = (unsigned)staged[seg0 + i].x >> 19;
        atomicAdd(&cnt[rl], 1);
    }
    __syncthreads();
    if (t < AROWS) pfx[t] = cnt[t];
    __syncthreads();
    for (int ofs = 1; ofs < AROWS; ofs <<= 1) {
        int x = (t >= ofs && t < AROWS) ? pfx[t - ofs] : 0;
        __syncthreads();
        if (t < AROWS) pfx[t] += x;       // inclusive prefix
        __syncthreads();
    }
    int rowbase = b << AB_SHIFT;
    if (t < AROWS && rowbase + t < n) endp[rowbase + t] = seg0 + pfx[t];
    __syncthreads();
    if (t < AROWS) cnt[t] = pfx[t] - cnt[t];   // running cursor (exclusive)
    __syncthreads();
    for (int i = t; i < len; i += SORT_T) {
        int2 p = staged[seg0 + i];
        int rl = (unsigned)p.x >> 19;
        int pos = atomicAdd(&cnt[rl], 1);
        int2 rec = make_int2(p.x & 0x7FFFF, p.y);
        if (pos < SORT_CAP) buf[pos] = rec;
        else pairs[seg0 + pos] = rec;
    }
    __syncthreads();
    int m = len < SORT_CAP ? len : SORT_CAP;
    for (int i = t; i < m; i += SORT_T) pairs[seg0 + i] = buf[i];
}

// ---------- fp32 -> bf16 table convert (e0) ----------
__global__ __launch_bounds__(256) void to_bf16(
    const float* __restrict__ u, const float* __restrict__ it,
    unsigned short* __restrict__ q, long long userD, long long totalD)
{
    long long stride = (long long)gridDim.x * 256 * 4;
    for (long long i = ((long long)blockIdx.x * 256 + threadIdx.x) * 4;
         i < totalD; i += stride) {
        float4 x = (i < userD) ? *(const float4*)(u + i)
                               : *(const float4*)(it + (i - userD));
        ushort4 o;
        o.x = f2bf(x.x); o.y = f2bf(x.y); o.z = f2bf(x.z); o.w = f2bf(x.w);
        *(ushort4*)(q + i) = o;
    }
}

// ---------- bf16-gather CSR spmm, fp32 accumulate ----------
// PASS 1: acc = e0(fp32) + r ; write bf16(r)
// PASS 2: acc += r          ; write bf16(r)
// PASS 3: acc += r
template <int PASS>
__global__ __launch_bounds__(256) void spmm_q(
    const int* __restrict__ endp, const int2* __restrict__ pairs,
    const unsigned short* __restrict__ tab,
    const float* __restrict__ u, const float* __restrict__ it, int user,
    float* __restrict__ acc, unsigned short* __restrict__ nextq, int n)
{
    int row = blockIdx.x * 16 + (threadIdx.x >> 4);
    if (row >= n) return;
    int l = threadIdx.x & 15;
    int start = row ? endp[row - 1] : 0;
    int end = endp[row];
    float ax = 0.f, ay = 0.f, az = 0.f, aw = 0.f;
    int e = start;
    for (; e + 2 <= end; e += 2) {
        int2 p0 = pairs[e];
        int2 p1 = pairs[e + 1];
        ushort4 q0 = ((const ushort4*)(tab + (size_t)p0.x * D))[l];
        ushort4 q1 = ((const ushort4*)(tab + (size_t)p1.x * D))[l];
        float v0 = __int_as_float(p0.y), v1 = __int_as_float(p1.y);
        ax = fmaf(v0, bf2f(q0.x), ax); ay = fmaf(v0, bf2f(q0.y), ay);
        az = fmaf(v0, bf2f(q0.z), az); aw = fmaf(v0, bf2f(q0.w), aw);
        ax = fmaf(v1, bf2f(q1.x), ax); ay = fmaf(v1, bf2f(q1.y), ay);
        az = fmaf(v1, bf2f(q1.z), az); aw = fmaf(v1, bf2f(q1.w), aw);
    }
    if (e < end) {
        int2 p = pairs[e];
        ushort4 q = ((const ushort4*)(tab + (size_t)p.x * D))[l];
        float v = __int_as_float(p.y);
        ax = fmaf(v, bf2f(q.x), ax); ay = fmaf(v, bf2f(q.y), ay);
        az = fmaf(v, bf2f(q.z), az); aw = fmaf(v, bf2f(q.w), aw);
    }
    size_t off = (size_t)row * D + l * 4;
    float4 a;
    if (PASS == 1) {
        const float* e0 = (row < user) ? u + (size_t)row * D
                                       : it + (size_t)(row - user) * D;
        float4 b0 = *(const float4*)(e0 + l * 4);
        a = make_float4(ax + b0.x, ay + b0.y, az + b0.z, aw + b0.w);
    } else {
        float4 prev = *(const float4*)(acc + off);
        a = make_float4(ax + prev.x, ay + prev.y, az + prev.z, aw + prev.w);
    }
    *(float4*)(acc + off) = a;
    if (PASS < 3) {
        ushort4 o;
        o.x = f2bf(ax); o.y = f2bf(ay); o.z = f2bf(az); o.w = f2bf(aw);
        *(ushort4*)(nextq + off) = o;
    }
}

// ---------- launch ----------
static inline size_t alignup(size_t x) { return (x + 255) & ~(size_t)255; }

extern "C" void kernel_launch(void* const* d_in, const int* in_sizes, int n_in,
                              void* d_out, int out_size, void* d_ws, size_t ws_size,
                              hipStream_t stream) {
    const int*   rows = (const int*)  d_in[0];
    const int*   cols = (const int*)  d_in[1];
    const float* vals = (const float*)d_in[2];
    const float* u    = (const float*)d_in[3];
    const float* it   = (const float*)d_in[4];

    const int nedges = in_sizes[0];
    const int user   = in_sizes[3] / D;
    const int item   = in_sizes[4] / D;
    const int n      = user + item;
    const int nab    = (n + AROWS - 1) >> AB_SHIFT;   // 1172

    float* acc = (float*)d_out;

    // workspace carve
    char* w = (char*)d_ws;
    int*  cnt  = (int*)w;  w += alignup((size_t)nab * sizeof(int));
    int*  bptr = (int*)w;  w += alignup((size_t)(nab + 1) * sizeof(int));
    int*  gcur = (int*)w;  w += alignup((size_t)nab * sizeof(int));
    int*  endp = (int*)w;  w += alignup((size_t)n * sizeof(int));
    int2* pairs = (int2*)w; w += alignup((size_t)nedges * sizeof(int2));
    // region X: staged (E*8B, dead after bucket_sort) then e1q (n*D*2B)
    char* regX = w;         w += alignup((size_t)nedges * sizeof(int2));
    // region Y: e0q then e2q (n*D*2B each)
    char* regY = w;
    int2* staged = (int2*)regX;
    unsigned short* e1q = (unsigned short*)regX;
    unsigned short* e0q = (unsigned short*)regY;
    unsigned short* e2q = (unsigned short*)regY;

    const int hblocks = (nedges + EPB - 1) / EPB;
    const int sblocks = (n + 15) / 16;
    const long long userD = (long long)user * D;
    const long long totalD = (long long)n * D;

    hipMemsetAsync(cnt, 0, (size_t)nab * sizeof(int), stream);
    bucket_hist<<<hblocks, 256, 0, stream>>>(rows, cnt, nedges, nab);
    scan_buckets<<<1, 1024, 0, stream>>>(cnt, bptr, gcur, nab, nedges);
    partition_edges<<<hblocks, 256, 0, stream>>>(rows, cols, vals, gcur, staged, nedges, nab);
    bucket_sort<<<nab, SORT_T, 0, stream>>>(bptr, staged, pairs, endp, n);
    to_bf16<<<2048, 256, 0, stream>>>(u, it, e0q, userD, totalD);

    // pass 1: acc = e0 + e1 ; e1q = bf16(e1)
    spmm_q<1><<<sblocks, 256, 0, stream>>>(
        endp, pairs, e0q, u, it, user, acc, e1q, n);
    // pass 2: acc += e2 ; e2q = bf16(e2)   (reuses region Y)
    spmm_q<2><<<sblocks, 256, 0, stream>>>(
        endp, pairs, e1q, u, it, user, acc, e2q, n);
    // pass 3: acc += e3
    spmm_q<3><<<sblocks, 256, 0, stream>>>(
        endp, pairs, e2q, u, it, user, acc, nullptr, n);
}

// Round 8
// 518.431 us; speedup vs baseline: 10.0438x; 1.1155x over previous
//
#include <hip/hip_runtime.h>

#define D 64
#define AB_SHIFT 9
#define AROWS 512                 // rows per bucket
#define NAB_MAX 640               // >= 586 buckets
#define CHP 3                     // ceil(NAB_MAX/256) bucket-chunks per thread
#define HEPB 4096                 // edges per hist block
#define P_EPB 4096                // edges per partition block
#define P_T 256
#define P_PER (P_EPB / P_T)       // 16
#define SORT_T 512
#define SORT_CAP 9472             // LDS record capacity (74 KB)

__device__ __forceinline__ unsigned short f2bf(float f) {
    unsigned u = __float_as_uint(f);
    return (unsigned short)((u + 0x7FFFu + ((u >> 16) & 1u)) >> 16);  // RNE
}
__device__ __forceinline__ float bflo(unsigned u) {
    return __uint_as_float(u << 16);
}
__device__ __forceinline__ float bfhi(unsigned u) {
    return __uint_as_float(u & 0xFFFF0000u);
}

// ---------- bucket histogram ----------
__global__ __launch_bounds__(256) void bucket_hist(
    const int* __restrict__ rows, int* __restrict__ cnt, int nedges, int nab)
{
    __shared__ int h[NAB_MAX];
    int t = threadIdx.x;
    for (int i = t; i < nab; i += 256) h[i] = 0;
    __syncthreads();
    int base = blockIdx.x * HEPB;
    #pragma unroll
    for (int i = 0; i < HEPB / 256; i++) {
        int e = base + i * 256 + t;
        if (e < nedges) atomicAdd(&h[rows[e] >> AB_SHIFT], 1);
    }
    __syncthreads();
    for (int i = t; i < nab; i += 256) if (h[i]) atomicAdd(&cnt[i], h[i]);
}

// ---------- exclusive scan of bucket counts (single block) ----------
__global__ __launch_bounds__(1024) void scan_buckets(
    const int* __restrict__ cnt, int* __restrict__ bptr, int* __restrict__ gcur,
    int nab, int nedges)
{
    __shared__ int lds[1024];
    int t = threadIdx.x;
    int i0 = 2 * t, i1 = 2 * t + 1;
    int a = (i0 < nab) ? cnt[i0] : 0;
    int b = (i1 < nab) ? cnt[i1] : 0;
    int s = a + b;
    lds[t] = s;
    __syncthreads();
    for (int ofs = 1; ofs < 1024; ofs <<= 1) {
        int x = (t >= ofs) ? lds[t - ofs] : 0;
        __syncthreads();
        lds[t] += x;
        __syncthreads();
    }
    int excl = lds[t] - s;
    if (i0 < nab) { bptr[i0] = excl;     gcur[i0] = excl; }
    if (i1 < nab) { bptr[i1] = excl + a; gcur[i1] = excl + a; }
    if (t == 0) bptr[nab] = nedges;
}

// ---------- partition v2: LDS-reordered multi-split ----------
// pk = (rank<<19) | (rowlocal<<10) | b   (rank<4096, rl<512, b<1024)
__global__ __launch_bounds__(P_T) void partition_edges(
    const int* __restrict__ rows, const int* __restrict__ cols,
    const float* __restrict__ vals, int* __restrict__ gcur,
    int2* __restrict__ staged, int nedges, int nab)
{
    __shared__ int h[NAB_MAX];        // counts -> delta (gbase - lofs)
    __shared__ int lofs[NAB_MAX];
    __shared__ int partial[P_T];
    __shared__ int mcount;
    __shared__ int2 sbuf[P_EPB];      // 32 KB
    __shared__ unsigned short bid[P_EPB]; // 8 KB
    int t = threadIdx.x;
    int base = blockIdx.x * P_EPB;
    for (int i = t; i < nab; i += P_T) h[i] = 0;
    __syncthreads();
    int pk[P_PER];
    #pragma unroll
    for (int i = 0; i < P_PER; i++) {
        int e = base + i * P_T + t;
        if (e < nedges) {
            int r = rows[e];
            int b = r >> AB_SHIFT;
            int rank = atomicAdd(&h[b], 1);
            pk[i] = (rank << 19) | ((r & (AROWS - 1)) << 10) | b;
        } else pk[i] = -1;
    }
    __syncthreads();
    // block-local exclusive scan of h -> lofs
    int s = 0;
    int b0 = t * CHP;
    #pragma unroll
    for (int j = 0; j < CHP; j++) { int b = b0 + j; if (b < nab) s += h[b]; }
    partial[t] = s;
    __syncthreads();
    for (int ofs = 1; ofs < P_T; ofs <<= 1) {
        int x = (t >= ofs) ? partial[t - ofs] : 0;
        __syncthreads();
        partial[t] += x;
        __syncthreads();
    }
    if (t == P_T - 1) mcount = partial[t];
    int run = partial[t] - s;
    #pragma unroll
    for (int j = 0; j < CHP; j++) {
        int b = b0 + j;
        if (b < nab) { lofs[b] = run; run += h[b]; }
    }
    __syncthreads();
    // reserve global ranges; h becomes delta = gbase - lofs
    for (int i = t; i < nab; i += P_T) {
        int c = h[i];
        if (c) { int gb = atomicAdd(&gcur[i], c); h[i] = gb - lofs[i]; }
    }
    __syncthreads();
    // sweep 2: place records into LDS in bucket-grouped order
    #pragma unroll
    for (int i = 0; i < P_PER; i++) {
        if (pk[i] < 0) continue;
        int e = base + i * P_T + t;
        int b = pk[i] & 1023;
        int rl = (pk[i] >> 10) & (AROWS - 1);
        int rank = (unsigned)pk[i] >> 19;
        int q = lofs[b] + rank;
        sbuf[q] = make_int2((rl << 19) | cols[e], __float_as_int(vals[e]));
        bid[q] = (unsigned short)b;
    }
    __syncthreads();
    // dump: consecutive lanes -> consecutive global addresses per segment
    int m = mcount;
    for (int q = t; q < m; q += P_T) {
        int b = bid[q];
        staged[h[b] + q] = sbuf[q];
    }
}

// ---------- in-LDS row sort of each bucket segment ----------
__global__ __launch_bounds__(SORT_T) void bucket_sort(
    const int* __restrict__ bptr, const int2* __restrict__ staged,
    int2* __restrict__ pairs, int* __restrict__ endp, int n)
{
    __shared__ int cnt[AROWS];
    __shared__ int pfx[AROWS];
    __shared__ int2 buf[SORT_CAP];
    int t = threadIdx.x;
    int b = blockIdx.x;
    int seg0 = bptr[b], seg1 = bptr[b + 1];
    int len = seg1 - seg0;
    cnt[t] = 0;
    __syncthreads();
    for (int i = t; i < len; i += SORT_T) {
        int rl = (unsigned)staged[seg0 + i].x >> 19;
        atomicAdd(&cnt[rl], 1);
    }
    __syncthreads();
    pfx[t] = cnt[t];
    __syncthreads();
    for (int ofs = 1; ofs < AROWS; ofs <<= 1) {
        int x = (t >= ofs) ? pfx[t - ofs] : 0;
        __syncthreads();
        pfx[t] += x;       // inclusive prefix
        __syncthreads();
    }
    int rowbase = b << AB_SHIFT;
    if (rowbase + t < n) endp[rowbase + t] = seg0 + pfx[t];
    cnt[t] = pfx[t] - cnt[t];   // running cursor (exclusive)
    __syncthreads();
    for (int i = t; i < len; i += SORT_T) {
        int2 p = staged[seg0 + i];
        int rl = (unsigned)p.x >> 19;
        int pos = atomicAdd(&cnt[rl], 1);
        int2 rec = make_int2(p.x & 0x7FFFF, p.y);
        if (pos < SORT_CAP) buf[pos] = rec;
        else pairs[seg0 + pos] = rec;
    }
    __syncthreads();
    int m = len < SORT_CAP ? len : SORT_CAP;
    for (int i = t; i < m; i += SORT_T) pairs[seg0 + i] = buf[i];
}

// ---------- fp32 -> bf16 table convert (e0) ----------
__global__ __launch_bounds__(256) void to_bf16(
    const float* __restrict__ u, const float* __restrict__ it,
    unsigned short* __restrict__ q, long long userD, long long totalD)
{
    long long stride = (long long)gridDim.x * 256 * 4;
    for (long long i = ((long long)blockIdx.x * 256 + threadIdx.x) * 4;
         i < totalD; i += stride) {
        float4 x = (i < userD) ? *(const float4*)(u + i)
                               : *(const float4*)(it + (i - userD));
        ushort4 o;
        o.x = f2bf(x.x); o.y = f2bf(x.y); o.z = f2bf(x.z); o.w = f2bf(x.w);
        *(ushort4*)(q + i) = o;
    }
}

// ---------- bf16-gather CSR spmm, 8 lanes/row, fp32 accumulate ----------
template <int PASS>
__global__ __launch_bounds__(256) void spmm_q(
    const int* __restrict__ endp, const int2* __restrict__ pairs,
    const unsigned short* __restrict__ tab,
    const float* __restrict__ u, const float* __restrict__ it, int user,
    float* __restrict__ acc, unsigned short* __restrict__ nextq, int n)
{
    int row = blockIdx.x * 32 + (threadIdx.x >> 3);
    if (row >= n) return;
    int l = threadIdx.x & 7;
    int start = row ? endp[row - 1] : 0;
    int end = endp[row];
    const uint4* tb = (const uint4*)tab;     // one row = 8 uint4
    float a0=0.f,a1=0.f,a2=0.f,a3=0.f,a4=0.f,a5=0.f,a6=0.f,a7=0.f;
    int e = start;
    for (; e + 2 <= end; e += 2) {
        int2 p0 = pairs[e];
        int2 p1 = pairs[e + 1];
        uint4 q0 = tb[(size_t)p0.x * 8 + l];
        uint4 q1 = tb[(size_t)p1.x * 8 + l];
        float v0 = __int_as_float(p0.y), v1 = __int_as_float(p1.y);
        a0 = fmaf(v0, bflo(q0.x), a0); a1 = fmaf(v0, bfhi(q0.x), a1);
        a2 = fmaf(v0, bflo(q0.y), a2); a3 = fmaf(v0, bfhi(q0.y), a3);
        a4 = fmaf(v0, bflo(q0.z), a4); a5 = fmaf(v0, bfhi(q0.z), a5);
        a6 = fmaf(v0, bflo(q0.w), a6); a7 = fmaf(v0, bfhi(q0.w), a7);
        a0 = fmaf(v1, bflo(q1.x), a0); a1 = fmaf(v1, bfhi(q1.x), a1);
        a2 = fmaf(v1, bflo(q1.y), a2); a3 = fmaf(v1, bfhi(q1.y), a3);
        a4 = fmaf(v1, bflo(q1.z), a4); a5 = fmaf(v1, bfhi(q1.z), a5);
        a6 = fmaf(v1, bflo(q1.w), a6); a7 = fmaf(v1, bfhi(q1.w), a7);
    }
    if (e < end) {
        int2 p = pairs[e];
        uint4 q0 = tb[(size_t)p.x * 8 + l];
        float v = __int_as_float(p.y);
        a0 = fmaf(v, bflo(q0.x), a0); a1 = fmaf(v, bfhi(q0.x), a1);
        a2 = fmaf(v, bflo(q0.y), a2); a3 = fmaf(v, bfhi(q0.y), a3);
        a4 = fmaf(v, bflo(q0.z), a4); a5 = fmaf(v, bfhi(q0.z), a5);
        a6 = fmaf(v, bflo(q0.w), a6); a7 = fmaf(v, bfhi(q0.w), a7);
    }
    size_t off = (size_t)row * D + l * 8;
    float4 r0 = make_float4(a0, a1, a2, a3);
    float4 r1 = make_float4(a4, a5, a6, a7);
    if (PASS == 1) {
        const float* e0 = ((row < user) ? u + (size_t)row * D
                                        : it + (size_t)(row - user) * D) + l * 8;
        float4 b0 = *(const float4*)e0;
        float4 b1 = *(const float4*)(e0 + 4);
        r0.x += b0.x; r0.y += b0.y; r0.z += b0.z; r0.w += b0.w;
        r1.x += b1.x; r1.y += b1.y; r1.z += b1.z; r1.w += b1.w;
    } else {
        float4 b0 = *(const float4*)(acc + off);
        float4 b1 = *(const float4*)(acc + off + 4);
        r0.x += b0.x; r0.y += b0.y; r0.z += b0.z; r0.w += b0.w;
        r1.x += b1.x; r1.y += b1.y; r1.z += b1.z; r1.w += b1.w;
    }
    *(float4*)(acc + off) = r0;
    *(float4*)(acc + off + 4) = r1;
    if (PASS < 3) {
        uint4 o;
        o.x = ((unsigned)f2bf(a1) << 16) | f2bf(a0);
        o.y = ((unsigned)f2bf(a3) << 16) | f2bf(a2);
        o.z = ((unsigned)f2bf(a5) << 16) | f2bf(a4);
        o.w = ((unsigned)f2bf(a7) << 16) | f2bf(a6);
        *(uint4*)(nextq + off) = o;
    }
}

// ---------- launch ----------
static inline size_t alignup(size_t x) { return (x + 255) & ~(size_t)255; }

extern "C" void kernel_launch(void* const* d_in, const int* in_sizes, int n_in,
                              void* d_out, int out_size, void* d_ws, size_t ws_size,
                              hipStream_t stream) {
    const int*   rows = (const int*)  d_in[0];
    const int*   cols = (const int*)  d_in[1];
    const float* vals = (const float*)d_in[2];
    const float* u    = (const float*)d_in[3];
    const float* it   = (const float*)d_in[4];

    const int nedges = in_sizes[0];
    const int user   = in_sizes[3] / D;
    const int item   = in_sizes[4] / D;
    const int n      = user + item;
    const int nab    = (n + AROWS - 1) >> AB_SHIFT;   // 586

    float* acc = (float*)d_out;

    // workspace carve
    char* w = (char*)d_ws;
    int*  cnt  = (int*)w;  w += alignup((size_t)nab * sizeof(int));
    int*  bptr = (int*)w;  w += alignup((size_t)(nab + 1) * sizeof(int));
    int*  gcur = (int*)w;  w += alignup((size_t)nab * sizeof(int));
    int*  endp = (int*)w;  w += alignup((size_t)n * sizeof(int));
    int2* pairs = (int2*)w; w += alignup((size_t)nedges * sizeof(int2));
    // region X: staged (E*8B, dead after bucket_sort) then e1q (n*D*2B)
    char* regX = w;         w += alignup((size_t)nedges * sizeof(int2));
    // region Y: e0q then e2q (n*D*2B each)
    char* regY = w;
    int2* staged = (int2*)regX;
    unsigned short* e1q = (unsigned short*)regX;
    unsigned short* e0q = (unsigned short*)regY;
    unsigned short* e2q = (unsigned short*)regY;

    const int hblocks = (nedges + HEPB - 1) / HEPB;
    const int pblocks = (nedges + P_EPB - 1) / P_EPB;
    const int sblocks = (n + 31) / 32;
    const long long userD = (long long)user * D;
    const long long totalD = (long long)n * D;

    hipMemsetAsync(cnt, 0, (size_t)nab * sizeof(int), stream);
    bucket_hist<<<hblocks, 256, 0, stream>>>(rows, cnt, nedges, nab);
    scan_buckets<<<1, 1024, 0, stream>>>(cnt, bptr, gcur, nab, nedges);
    partition_edges<<<pblocks, P_T, 0, stream>>>(rows, cols, vals, gcur, staged, nedges, nab);
    bucket_sort<<<nab, SORT_T, 0, stream>>>(bptr, staged, pairs, endp, n);
    to_bf16<<<2048, 256, 0, stream>>>(u, it, e0q, userD, totalD);

    // pass 1: acc = e0 + e1 ; e1q = bf16(e1)
    spmm_q<1><<<sblocks, 256, 0, stream>>>(
        endp, pairs, e0q, u, it, user, acc, e1q, n);
    // pass 2: acc += e2 ; e2q = bf16(e2)
    spmm_q<2><<<sblocks, 256, 0, stream>>>(
        endp, pairs, e1q, u, it, user, acc, e2q, n);
    // pass 3: acc += e3
    spmm_q<3><<<sblocks, 256, 0, stream>>>(
        endp, pairs, e2q, u, it, user, acc, nullptr, n);
}

// Round 9
// 475.817 us; speedup vs baseline: 10.9433x; 1.0896x over previous
//
#include <hip/hip_runtime.h>

#define D 64
#define AB_SHIFT 9
#define AROWS 512                 // rows per bucket
#define NAB_MAX 640               // >= 586 buckets
#define CHP 3                     // ceil(NAB_MAX/256) bucket-chunks per thread
#define HEPB 4096                 // edges per hist block
#define P_EPB 4096                // edges per partition block
#define P_T 256
#define P_PER (P_EPB / P_T)       // 16
#define SORT_T 512
#define SORT_CAP 9472             // LDS record capacity (74 KB)

__device__ __forceinline__ unsigned short f2bf(float f) {
    unsigned u = __float_as_uint(f);
    return (unsigned short)((u + 0x7FFFu + ((u >> 16) & 1u)) >> 16);  // RNE
}
__device__ __forceinline__ float bflo(unsigned u) {
    return __uint_as_float(u << 16);
}
__device__ __forceinline__ float bfhi(unsigned u) {
    return __uint_as_float(u & 0xFFFF0000u);
}

// ---------- bucket histogram ----------
__global__ __launch_bounds__(256) void bucket_hist(
    const int* __restrict__ rows, int* __restrict__ cnt, int nedges, int nab)
{
    __shared__ int h[NAB_MAX];
    int t = threadIdx.x;
    for (int i = t; i < nab; i += 256) h[i] = 0;
    __syncthreads();
    int base = blockIdx.x * HEPB;
    #pragma unroll
    for (int i = 0; i < HEPB / 256; i++) {
        int e = base + i * 256 + t;
        if (e < nedges) atomicAdd(&h[rows[e] >> AB_SHIFT], 1);
    }
    __syncthreads();
    for (int i = t; i < nab; i += 256) if (h[i]) atomicAdd(&cnt[i], h[i]);
}

// ---------- exclusive scan of bucket counts (single block) ----------
__global__ __launch_bounds__(1024) void scan_buckets(
    const int* __restrict__ cnt, int* __restrict__ bptr, int* __restrict__ gcur,
    int nab, int nedges)
{
    __shared__ int lds[1024];
    int t = threadIdx.x;
    int i0 = 2 * t, i1 = 2 * t + 1;
    int a = (i0 < nab) ? cnt[i0] : 0;
    int b = (i1 < nab) ? cnt[i1] : 0;
    int s = a + b;
    lds[t] = s;
    __syncthreads();
    for (int ofs = 1; ofs < 1024; ofs <<= 1) {
        int x = (t >= ofs) ? lds[t - ofs] : 0;
        __syncthreads();
        lds[t] += x;
        __syncthreads();
    }
    int excl = lds[t] - s;
    if (i0 < nab) { bptr[i0] = excl;     gcur[i0] = excl; }
    if (i1 < nab) { bptr[i1] = excl + a; gcur[i1] = excl + a; }
    if (t == 0) bptr[nab] = nedges;
}

// ---------- partition v2: LDS-reordered multi-split ----------
__global__ __launch_bounds__(P_T) void partition_edges(
    const int* __restrict__ rows, const int* __restrict__ cols,
    const float* __restrict__ vals, int* __restrict__ gcur,
    int2* __restrict__ staged, int nedges, int nab)
{
    __shared__ int h[NAB_MAX];        // counts -> delta (gbase - lofs)
    __shared__ int lofs[NAB_MAX];
    __shared__ int partial[P_T];
    __shared__ int mcount;
    __shared__ int2 sbuf[P_EPB];      // 32 KB
    __shared__ unsigned short bid[P_EPB]; // 8 KB
    int t = threadIdx.x;
    int base = blockIdx.x * P_EPB;
    for (int i = t; i < nab; i += P_T) h[i] = 0;
    __syncthreads();
    int pk[P_PER];
    #pragma unroll
    for (int i = 0; i < P_PER; i++) {
        int e = base + i * P_T + t;
        if (e < nedges) {
            int r = rows[e];
            int b = r >> AB_SHIFT;
            int rank = atomicAdd(&h[b], 1);
            pk[i] = (rank << 19) | ((r & (AROWS - 1)) << 10) | b;
        } else pk[i] = -1;
    }
    __syncthreads();
    int s = 0;
    int b0 = t * CHP;
    #pragma unroll
    for (int j = 0; j < CHP; j++) { int b = b0 + j; if (b < nab) s += h[b]; }
    partial[t] = s;
    __syncthreads();
    for (int ofs = 1; ofs < P_T; ofs <<= 1) {
        int x = (t >= ofs) ? partial[t - ofs] : 0;
        __syncthreads();
        partial[t] += x;
        __syncthreads();
    }
    if (t == P_T - 1) mcount = partial[t];
    int run = partial[t] - s;
    #pragma unroll
    for (int j = 0; j < CHP; j++) {
        int b = b0 + j;
        if (b < nab) { lofs[b] = run; run += h[b]; }
    }
    __syncthreads();
    for (int i = t; i < nab; i += P_T) {
        int c = h[i];
        if (c) { int gb = atomicAdd(&gcur[i], c); h[i] = gb - lofs[i]; }
    }
    __syncthreads();
    #pragma unroll
    for (int i = 0; i < P_PER; i++) {
        if (pk[i] < 0) continue;
        int e = base + i * P_T + t;
        int b = pk[i] & 1023;
        int rl = (pk[i] >> 10) & (AROWS - 1);
        int rank = (unsigned)pk[i] >> 19;
        int q = lofs[b] + rank;
        sbuf[q] = make_int2((rl << 19) | cols[e], __float_as_int(vals[e]));
        bid[q] = (unsigned short)b;
    }
    __syncthreads();
    int m = mcount;
    for (int q = t; q < m; q += P_T) {
        int b = bid[q];
        staged[h[b] + q] = sbuf[q];
    }
}

// ---------- in-LDS row sort of each bucket segment ----------
__global__ __launch_bounds__(SORT_T) void bucket_sort(
    const int* __restrict__ bptr, const int2* __restrict__ staged,
    int2* __restrict__ pairs, int* __restrict__ endp, int n)
{
    __shared__ int cnt[AROWS];
    __shared__ int pfx[AROWS];
    __shared__ int2 buf[SORT_CAP];
    int t = threadIdx.x;
    int b = blockIdx.x;
    int seg0 = bptr[b], seg1 = bptr[b + 1];
    int len = seg1 - seg0;
    cnt[t] = 0;
    __syncthreads();
    for (int i = t; i < len; i += SORT_T) {
        int rl = (unsigned)staged[seg0 + i].x >> 19;
        atomicAdd(&cnt[rl], 1);
    }
    __syncthreads();
    pfx[t] = cnt[t];
    __syncthreads();
    for (int ofs = 1; ofs < AROWS; ofs <<= 1) {
        int x = (t >= ofs) ? pfx[t - ofs] : 0;
        __syncthreads();
        pfx[t] += x;       // inclusive prefix
        __syncthreads();
    }
    int rowbase = b << AB_SHIFT;
    if (rowbase + t < n) endp[rowbase + t] = seg0 + pfx[t];
    cnt[t] = pfx[t] - cnt[t];   // running cursor (exclusive)
    __syncthreads();
    for (int i = t; i < len; i += SORT_T) {
        int2 p = staged[seg0 + i];
        int rl = (unsigned)p.x >> 19;
        int pos = atomicAdd(&cnt[rl], 1);
        int2 rec = make_int2(p.x & 0x7FFFF, p.y);
        if (pos < SORT_CAP) buf[pos] = rec;
        else pairs[seg0 + pos] = rec;
    }
    __syncthreads();
    int m = len < SORT_CAP ? len : SORT_CAP;
    for (int i = t; i < m; i += SORT_T) pairs[seg0 + i] = buf[i];
}

// ---------- fp32 -> bf16 table convert (e0) ----------
__global__ __launch_bounds__(256) void to_bf16(
    const float* __restrict__ u, const float* __restrict__ it,
    unsigned short* __restrict__ q, long long userD, long long totalD)
{
    long long stride = (long long)gridDim.x * 256 * 4;
    for (long long i = ((long long)blockIdx.x * 256 + threadIdx.x) * 4;
         i < totalD; i += stride) {
        float4 x = (i < userD) ? *(const float4*)(u + i)
                               : *(const float4*)(it + (i - userD));
        ushort4 o;
        o.x = f2bf(x.x); o.y = f2bf(x.y); o.z = f2bf(x.z); o.w = f2bf(x.w);
        *(ushort4*)(q + i) = o;
    }
}

// ---------- gather core: r = A(row) . tab, 8 lanes/row, 4-deep ----------
__device__ __forceinline__ void gather_row(
    const int* __restrict__ endp, const int2* __restrict__ pairs,
    const uint4* __restrict__ tb, int row, int l,
    float& a0, float& a1, float& a2, float& a3,
    float& a4, float& a5, float& a6, float& a7)
{
    int start = row ? endp[row - 1] : 0;
    int end = endp[row];
    int e = start;
    for (; e + 4 <= end; e += 4) {
        int2 p0 = pairs[e], p1 = pairs[e + 1], p2 = pairs[e + 2], p3 = pairs[e + 3];
        uint4 q0 = tb[(size_t)p0.x * 8 + l];
        uint4 q1 = tb[(size_t)p1.x * 8 + l];
        uint4 q2 = tb[(size_t)p2.x * 8 + l];
        uint4 q3 = tb[(size_t)p3.x * 8 + l];
        float v0 = __int_as_float(p0.y), v1 = __int_as_float(p1.y);
        float v2 = __int_as_float(p2.y), v3 = __int_as_float(p3.y);
        a0 = fmaf(v0, bflo(q0.x), a0); a1 = fmaf(v0, bfhi(q0.x), a1);
        a2 = fmaf(v0, bflo(q0.y), a2); a3 = fmaf(v0, bfhi(q0.y), a3);
        a4 = fmaf(v0, bflo(q0.z), a4); a5 = fmaf(v0, bfhi(q0.z), a5);
        a6 = fmaf(v0, bflo(q0.w), a6); a7 = fmaf(v0, bfhi(q0.w), a7);
        a0 = fmaf(v1, bflo(q1.x), a0); a1 = fmaf(v1, bfhi(q1.x), a1);
        a2 = fmaf(v1, bflo(q1.y), a2); a3 = fmaf(v1, bfhi(q1.y), a3);
        a4 = fmaf(v1, bflo(q1.z), a4); a5 = fmaf(v1, bfhi(q1.z), a5);
        a6 = fmaf(v1, bflo(q1.w), a6); a7 = fmaf(v1, bfhi(q1.w), a7);
        a0 = fmaf(v2, bflo(q2.x), a0); a1 = fmaf(v2, bfhi(q2.x), a1);
        a2 = fmaf(v2, bflo(q2.y), a2); a3 = fmaf(v2, bfhi(q2.y), a3);
        a4 = fmaf(v2, bflo(q2.z), a4); a5 = fmaf(v2, bfhi(q2.z), a5);
        a6 = fmaf(v2, bflo(q2.w), a6); a7 = fmaf(v2, bfhi(q2.w), a7);
        a0 = fmaf(v3, bflo(q3.x), a0); a1 = fmaf(v3, bfhi(q3.x), a1);
        a2 = fmaf(v3, bflo(q3.y), a2); a3 = fmaf(v3, bfhi(q3.y), a3);
        a4 = fmaf(v3, bflo(q3.z), a4); a5 = fmaf(v3, bfhi(q3.z), a5);
        a6 = fmaf(v3, bflo(q3.w), a6); a7 = fmaf(v3, bfhi(q3.w), a7);
    }
    for (; e < end; ++e) {
        int2 p = pairs[e];
        uint4 q0 = tb[(size_t)p.x * 8 + l];
        float v = __int_as_float(p.y);
        a0 = fmaf(v, bflo(q0.x), a0); a1 = fmaf(v, bfhi(q0.x), a1);
        a2 = fmaf(v, bflo(q0.y), a2); a3 = fmaf(v, bfhi(q0.y), a3);
        a4 = fmaf(v, bflo(q0.z), a4); a5 = fmaf(v, bfhi(q0.z), a5);
        a6 = fmaf(v, bflo(q0.w), a6); a7 = fmaf(v, bfhi(q0.w), a7);
    }
}

// ---------- mid pass: outq = bf16(A . tab), no acc traffic ----------
__global__ __launch_bounds__(256) void spmm_mid(
    const int* __restrict__ endp, const int2* __restrict__ pairs,
    const unsigned short* __restrict__ tab,
    unsigned short* __restrict__ outq, int n)
{
    int row = blockIdx.x * 32 + (threadIdx.x >> 3);
    if (row >= n) return;
    int l = threadIdx.x & 7;
    float a0=0.f,a1=0.f,a2=0.f,a3=0.f,a4=0.f,a5=0.f,a6=0.f,a7=0.f;
    gather_row(endp, pairs, (const uint4*)tab, row, l, a0,a1,a2,a3,a4,a5,a6,a7);
    uint4 o;
    o.x = ((unsigned)f2bf(a1) << 16) | f2bf(a0);
    o.y = ((unsigned)f2bf(a3) << 16) | f2bf(a2);
    o.z = ((unsigned)f2bf(a5) << 16) | f2bf(a4);
    o.w = ((unsigned)f2bf(a7) << 16) | f2bf(a6);
    *(uint4*)(outq + (size_t)row * D + l * 8) = o;
}

// ---------- final pass: acc = e0(fp32) + e1q + e2q + A . e2q ----------
__global__ __launch_bounds__(256) void spmm_final(
    const int* __restrict__ endp, const int2* __restrict__ pairs,
    const unsigned short* __restrict__ e2q, const unsigned short* __restrict__ e1q,
    const float* __restrict__ u, const float* __restrict__ it, int user,
    float* __restrict__ acc, int n)
{
    int row = blockIdx.x * 32 + (threadIdx.x >> 3);
    if (row >= n) return;
    int l = threadIdx.x & 7;
    float a0=0.f,a1=0.f,a2=0.f,a3=0.f,a4=0.f,a5=0.f,a6=0.f,a7=0.f;
    gather_row(endp, pairs, (const uint4*)e2q, row, l, a0,a1,a2,a3,a4,a5,a6,a7);
    size_t off = (size_t)row * D + l * 8;
    const float* e0 = ((row < user) ? u + (size_t)row * D
                                    : it + (size_t)(row - user) * D) + l * 8;
    float4 b0 = *(const float4*)e0;
    float4 b1 = *(const float4*)(e0 + 4);
    uint4 q1 = *(const uint4*)(e1q + off);
    uint4 q2 = *(const uint4*)(e2q + off);
    float4 r0, r1;
    r0.x = a0 + b0.x + bflo(q1.x) + bflo(q2.x);
    r0.y = a1 + b0.y + bfhi(q1.x) + bfhi(q2.x);
    r0.z = a2 + b0.z + bflo(q1.y) + bflo(q2.y);
    r0.w = a3 + b0.w + bfhi(q1.y) + bfhi(q2.y);
    r1.x = a4 + b1.x + bflo(q1.z) + bflo(q2.z);
    r1.y = a5 + b1.y + bfhi(q1.z) + bfhi(q2.z);
    r1.z = a6 + b1.z + bflo(q1.w) + bflo(q2.w);
    r1.w = a7 + b1.w + bfhi(q1.w) + bfhi(q2.w);
    *(float4*)(acc + off) = r0;
    *(float4*)(acc + off + 4) = r1;
}

// ---------- launch ----------
static inline size_t alignup(size_t x) { return (x + 255) & ~(size_t)255; }

extern "C" void kernel_launch(void* const* d_in, const int* in_sizes, int n_in,
                              void* d_out, int out_size, void* d_ws, size_t ws_size,
                              hipStream_t stream) {
    const int*   rows = (const int*)  d_in[0];
    const int*   cols = (const int*)  d_in[1];
    const float* vals = (const float*)d_in[2];
    const float* u    = (const float*)d_in[3];
    const float* it   = (const float*)d_in[4];

    const int nedges = in_sizes[0];
    const int user   = in_sizes[3] / D;
    const int item   = in_sizes[4] / D;
    const int n      = user + item;
    const int nab    = (n + AROWS - 1) >> AB_SHIFT;   // 586

    float* acc = (float*)d_out;

    // workspace carve
    char* w = (char*)d_ws;
    int*  cnt  = (int*)w;  w += alignup((size_t)nab * sizeof(int));
    int*  bptr = (int*)w;  w += alignup((size_t)(nab + 1) * sizeof(int));
    int*  gcur = (int*)w;  w += alignup((size_t)nab * sizeof(int));
    int*  endp = (int*)w;  w += alignup((size_t)n * sizeof(int));
    int2* pairs = (int2*)w; w += alignup((size_t)nedges * sizeof(int2));
    // region X: staged (E*8B, dead after bucket_sort) then e1q (n*D*2B)
    char* regX = w;         w += alignup((size_t)nedges * sizeof(int2));
    // region Y: e0q (dead after pass 1) then e2q (n*D*2B each)
    char* regY = w;
    int2* staged = (int2*)regX;
    unsigned short* e1q = (unsigned short*)regX;
    unsigned short* e0q = (unsigned short*)regY;
    unsigned short* e2q = (unsigned short*)regY;

    const int hblocks = (nedges + HEPB - 1) / HEPB;
    const int pblocks = (nedges + P_EPB - 1) / P_EPB;
    const int sblocks = (n + 31) / 32;
    const long long userD = (long long)user * D;
    const long long totalD = (long long)n * D;

    hipMemsetAsync(cnt, 0, (size_t)nab * sizeof(int), stream);
    bucket_hist<<<hblocks, 256, 0, stream>>>(rows, cnt, nedges, nab);
    scan_buckets<<<1, 1024, 0, stream>>>(cnt, bptr, gcur, nab, nedges);
    partition_edges<<<pblocks, P_T, 0, stream>>>(rows, cols, vals, gcur, staged, nedges, nab);
    bucket_sort<<<nab, SORT_T, 0, stream>>>(bptr, staged, pairs, endp, n);
    to_bf16<<<2048, 256, 0, stream>>>(u, it, e0q, userD, totalD);

    // pass 1: e1q = bf16(A.e0)
    spmm_mid<<<sblocks, 256, 0, stream>>>(endp, pairs, e0q, e1q, n);
    // pass 2: e2q = bf16(A.e1)   (e0q dead, regY reused as e2q)
    spmm_mid<<<sblocks, 256, 0, stream>>>(endp, pairs, e1q, e2q, n);
    // pass 3: acc = e0 + e1 + e2 + A.e2
    spmm_final<<<sblocks, 256, 0, stream>>>(
        endp, pairs, e2q, e1q, u, it, user, acc, n);
}

// Round 10
// 470.541 us; speedup vs baseline: 11.0660x; 1.0112x over previous
//
#include <hip/hip_runtime.h>

#define D 64
#define AB_SHIFT 9
#define AROWS 512                 // rows per bucket
#define NAB_MAX 640               // >= 586 buckets
#define CHP 3                     // ceil(NAB_MAX/256) bucket-chunks per thread
#define HEPB 4096                 // edges per hist block
#define P_EPB 4096                // edges per partition block
#define P_T 256
#define P_PER (P_EPB / P_T)       // 16
#define SORT_T 512
#define SORT_CAP 9472             // LDS record capacity (74 KB)

__device__ __forceinline__ unsigned short f2bf(float f) {
    unsigned u = __float_as_uint(f);
    return (unsigned short)((u + 0x7FFFu + ((u >> 16) & 1u)) >> 16);  // RNE
}
__device__ __forceinline__ float bflo(unsigned u) {
    return __uint_as_float(u << 16);
}
__device__ __forceinline__ float bfhi(unsigned u) {
    return __uint_as_float(u & 0xFFFF0000u);
}

// ---------- fused: bucket histogram + fp32->bf16 table convert ----------
__global__ __launch_bounds__(256) void hist_conv(
    const int* __restrict__ rows, int* __restrict__ cnt, int nedges, int nab,
    const float* __restrict__ u, const float* __restrict__ it,
    unsigned short* __restrict__ q, long long userD, long long totalD)
{
    __shared__ int h[NAB_MAX];
    int t = threadIdx.x;
    for (int i = t; i < nab; i += 256) h[i] = 0;
    __syncthreads();
    int base = blockIdx.x * HEPB;
    #pragma unroll
    for (int i = 0; i < HEPB / 256; i++) {
        int e = base + i * 256 + t;
        if (e < nedges) atomicAdd(&h[rows[e] >> AB_SHIFT], 1);
    }
    __syncthreads();
    for (int i = t; i < nab; i += 256) if (h[i]) atomicAdd(&cnt[i], h[i]);
    // convert phase (independent of hist)
    long long stride = (long long)gridDim.x * 256 * 4;
    for (long long i = ((long long)blockIdx.x * 256 + t) * 4; i < totalD; i += stride) {
        float4 x = (i < userD) ? *(const float4*)(u + i)
                               : *(const float4*)(it + (i - userD));
        ushort4 o;
        o.x = f2bf(x.x); o.y = f2bf(x.y); o.z = f2bf(x.z); o.w = f2bf(x.w);
        *(ushort4*)(q + i) = o;
    }
}

// ---------- exclusive scan of bucket counts (single block) ----------
__global__ __launch_bounds__(1024) void scan_buckets(
    const int* __restrict__ cnt, int* __restrict__ bptr, int* __restrict__ gcur,
    int nab, int nedges)
{
    __shared__ int lds[1024];
    int t = threadIdx.x;
    int i0 = 2 * t, i1 = 2 * t + 1;
    int a = (i0 < nab) ? cnt[i0] : 0;
    int b = (i1 < nab) ? cnt[i1] : 0;
    int s = a + b;
    lds[t] = s;
    __syncthreads();
    for (int ofs = 1; ofs < 1024; ofs <<= 1) {
        int x = (t >= ofs) ? lds[t - ofs] : 0;
        __syncthreads();
        lds[t] += x;
        __syncthreads();
    }
    int excl = lds[t] - s;
    if (i0 < nab) { bptr[i0] = excl;     gcur[i0] = excl; }
    if (i1 < nab) { bptr[i1] = excl + a; gcur[i1] = excl + a; }
    if (t == 0) bptr[nab] = nedges;
}

// ---------- partition v2: LDS-reordered multi-split ----------
__global__ __launch_bounds__(P_T) void partition_edges(
    const int* __restrict__ rows, const int* __restrict__ cols,
    const float* __restrict__ vals, int* __restrict__ gcur,
    int2* __restrict__ staged, int nedges, int nab)
{
    __shared__ int h[NAB_MAX];        // counts -> delta (gbase - lofs)
    __shared__ int lofs[NAB_MAX];
    __shared__ int partial[P_T];
    __shared__ int mcount;
    __shared__ int2 sbuf[P_EPB];      // 32 KB
    __shared__ unsigned short bid[P_EPB]; // 8 KB
    int t = threadIdx.x;
    int base = blockIdx.x * P_EPB;
    for (int i = t; i < nab; i += P_T) h[i] = 0;
    __syncthreads();
    int pk[P_PER];
    #pragma unroll
    for (int i = 0; i < P_PER; i++) {
        int e = base + i * P_T + t;
        if (e < nedges) {
            int r = rows[e];
            int b = r >> AB_SHIFT;
            int rank = atomicAdd(&h[b], 1);
            pk[i] = (rank << 19) | ((r & (AROWS - 1)) << 10) | b;
        } else pk[i] = -1;
    }
    __syncthreads();
    int s = 0;
    int b0 = t * CHP;
    #pragma unroll
    for (int j = 0; j < CHP; j++) { int b = b0 + j; if (b < nab) s += h[b]; }
    partial[t] = s;
    __syncthreads();
    for (int ofs = 1; ofs < P_T; ofs <<= 1) {
        int x = (t >= ofs) ? partial[t - ofs] : 0;
        __syncthreads();
        partial[t] += x;
        __syncthreads();
    }
    if (t == P_T - 1) mcount = partial[t];
    int run = partial[t] - s;
    #pragma unroll
    for (int j = 0; j < CHP; j++) {
        int b = b0 + j;
        if (b < nab) { lofs[b] = run; run += h[b]; }
    }
    __syncthreads();
    for (int i = t; i < nab; i += P_T) {
        int c = h[i];
        if (c) { int gb = atomicAdd(&gcur[i], c); h[i] = gb - lofs[i]; }
    }
    __syncthreads();
    #pragma unroll
    for (int i = 0; i < P_PER; i++) {
        if (pk[i] < 0) continue;
        int e = base + i * P_T + t;
        int b = pk[i] & 1023;
        int rl = (pk[i] >> 10) & (AROWS - 1);
        int rank = (unsigned)pk[i] >> 19;
        int q = lofs[b] + rank;
        sbuf[q] = make_int2((rl << 19) | cols[e], __float_as_int(vals[e]));
        bid[q] = (unsigned short)b;
    }
    __syncthreads();
    int m = mcount;
    for (int q = t; q < m; q += P_T) {
        int b = bid[q];
        staged[h[b] + q] = sbuf[q];
    }
}

// ---------- in-LDS row sort of each bucket segment ----------
__global__ __launch_bounds__(SORT_T) void bucket_sort(
    const int* __restrict__ bptr, const int2* __restrict__ staged,
    int2* __restrict__ pairs, int* __restrict__ endp, int n)
{
    __shared__ int cnt[AROWS];
    __shared__ int pfx[AROWS];
    __shared__ int2 buf[SORT_CAP];
    int t = threadIdx.x;
    int b = blockIdx.x;
    int seg0 = bptr[b], seg1 = bptr[b + 1];
    int len = seg1 - seg0;
    cnt[t] = 0;
    __syncthreads();
    for (int i = t; i < len; i += SORT_T) {
        int rl = (unsigned)staged[seg0 + i].x >> 19;
        atomicAdd(&cnt[rl], 1);
    }
    __syncthreads();
    pfx[t] = cnt[t];
    __syncthreads();
    for (int ofs = 1; ofs < AROWS; ofs <<= 1) {
        int x = (t >= ofs) ? pfx[t - ofs] : 0;
        __syncthreads();
        pfx[t] += x;       // inclusive prefix
        __syncthreads();
    }
    int rowbase = b << AB_SHIFT;
    if (rowbase + t < n) endp[rowbase + t] = seg0 + pfx[t];
    cnt[t] = pfx[t] - cnt[t];   // running cursor (exclusive)
    __syncthreads();
    for (int i = t; i < len; i += SORT_T) {
        int2 p = staged[seg0 + i];
        int rl = (unsigned)p.x >> 19;
        int pos = atomicAdd(&cnt[rl], 1);
        int2 rec = make_int2(p.x & 0x7FFFF, p.y);
        if (pos < SORT_CAP) buf[pos] = rec;
        else pairs[seg0 + pos] = rec;
    }
    __syncthreads();
    int m = len < SORT_CAP ? len : SORT_CAP;
    for (int i = t; i < m; i += SORT_T) pairs[seg0 + i] = buf[i];
}

// ---------- gather core: r = A(row) . tab, 8 lanes/row, 4-deep ----------
__device__ __forceinline__ void gather_row(
    const int* __restrict__ endp, const int2* __restrict__ pairs,
    const uint4* __restrict__ tb, int row, int l,
    float& a0, float& a1, float& a2, float& a3,
    float& a4, float& a5, float& a6, float& a7)
{
    int start = row ? endp[row - 1] : 0;
    int end = endp[row];
    int e = start;
    for (; e + 4 <= end; e += 4) {
        int2 p0 = pairs[e], p1 = pairs[e + 1], p2 = pairs[e + 2], p3 = pairs[e + 3];
        uint4 q0 = tb[(size_t)p0.x * 8 + l];
        uint4 q1 = tb[(size_t)p1.x * 8 + l];
        uint4 q2 = tb[(size_t)p2.x * 8 + l];
        uint4 q3 = tb[(size_t)p3.x * 8 + l];
        float v0 = __int_as_float(p0.y), v1 = __int_as_float(p1.y);
        float v2 = __int_as_float(p2.y), v3 = __int_as_float(p3.y);
        a0 = fmaf(v0, bflo(q0.x), a0); a1 = fmaf(v0, bfhi(q0.x), a1);
        a2 = fmaf(v0, bflo(q0.y), a2); a3 = fmaf(v0, bfhi(q0.y), a3);
        a4 = fmaf(v0, bflo(q0.z), a4); a5 = fmaf(v0, bfhi(q0.z), a5);
        a6 = fmaf(v0, bflo(q0.w), a6); a7 = fmaf(v0, bfhi(q0.w), a7);
        a0 = fmaf(v1, bflo(q1.x), a0); a1 = fmaf(v1, bfhi(q1.x), a1);
        a2 = fmaf(v1, bflo(q1.y), a2); a3 = fmaf(v1, bfhi(q1.y), a3);
        a4 = fmaf(v1, bflo(q1.z), a4); a5 = fmaf(v1, bfhi(q1.z), a5);
        a6 = fmaf(v1, bflo(q1.w), a6); a7 = fmaf(v1, bfhi(q1.w), a7);
        a0 = fmaf(v2, bflo(q2.x), a0); a1 = fmaf(v2, bfhi(q2.x), a1);
        a2 = fmaf(v2, bflo(q2.y), a2); a3 = fmaf(v2, bfhi(q2.y), a3);
        a4 = fmaf(v2, bflo(q2.z), a4); a5 = fmaf(v2, bfhi(q2.z), a5);
        a6 = fmaf(v2, bflo(q2.w), a6); a7 = fmaf(v2, bfhi(q2.w), a7);
        a0 = fmaf(v3, bflo(q3.x), a0); a1 = fmaf(v3, bfhi(q3.x), a1);
        a2 = fmaf(v3, bflo(q3.y), a2); a3 = fmaf(v3, bfhi(q3.y), a3);
        a4 = fmaf(v3, bflo(q3.z), a4); a5 = fmaf(v3, bfhi(q3.z), a5);
        a6 = fmaf(v3, bflo(q3.w), a6); a7 = fmaf(v3, bfhi(q3.w), a7);
    }
    for (; e < end; ++e) {
        int2 p = pairs[e];
        uint4 q0 = tb[(size_t)p.x * 8 + l];
        float v = __int_as_float(p.y);
        a0 = fmaf(v, bflo(q0.x), a0); a1 = fmaf(v, bfhi(q0.x), a1);
        a2 = fmaf(v, bflo(q0.y), a2); a3 = fmaf(v, bfhi(q0.y), a3);
        a4 = fmaf(v, bflo(q0.z), a4); a5 = fmaf(v, bfhi(q0.z), a5);
        a6 = fmaf(v, bflo(q0.w), a6); a7 = fmaf(v, bfhi(q0.w), a7);
    }
}

// ---------- mid pass: outq = bf16(A . tab), no acc traffic ----------
__global__ __launch_bounds__(256) void spmm_mid(
    const int* __restrict__ endp, const int2* __restrict__ pairs,
    const unsigned short* __restrict__ tab,
    unsigned short* __restrict__ outq, int n)
{
    int row = blockIdx.x * 32 + (threadIdx.x >> 3);
    if (row >= n) return;
    int l = threadIdx.x & 7;
    float a0=0.f,a1=0.f,a2=0.f,a3=0.f,a4=0.f,a5=0.f,a6=0.f,a7=0.f;
    gather_row(endp, pairs, (const uint4*)tab, row, l, a0,a1,a2,a3,a4,a5,a6,a7);
    uint4 o;
    o.x = ((unsigned)f2bf(a1) << 16) | f2bf(a0);
    o.y = ((unsigned)f2bf(a3) << 16) | f2bf(a2);
    o.z = ((unsigned)f2bf(a5) << 16) | f2bf(a4);
    o.w = ((unsigned)f2bf(a7) << 16) | f2bf(a6);
    *(uint4*)(outq + (size_t)row * D + l * 8) = o;
}

// ---------- final pass: acc = e0 + e1q + e2q + A . e2q ----------
// e0q != nullptr: read bf16 e0 snapshot (38 MB); else fp32 u/it (77 MB).
__global__ __launch_bounds__(256) void spmm_final(
    const int* __restrict__ endp, const int2* __restrict__ pairs,
    const unsigned short* __restrict__ e2q, const unsigned short* __restrict__ e1q,
    const unsigned short* __restrict__ e0q,
    const float* __restrict__ u, const float* __restrict__ it, int user,
    float* __restrict__ acc, int n)
{
    int row = blockIdx.x * 32 + (threadIdx.x >> 3);
    if (row >= n) return;
    int l = threadIdx.x & 7;
    float a0=0.f,a1=0.f,a2=0.f,a3=0.f,a4=0.f,a5=0.f,a6=0.f,a7=0.f;
    gather_row(endp, pairs, (const uint4*)e2q, row, l, a0,a1,a2,a3,a4,a5,a6,a7);
    size_t off = (size_t)row * D + l * 8;
    float4 b0, b1;
    if (e0q) {
        uint4 q0 = *(const uint4*)(e0q + off);
        b0 = make_float4(bflo(q0.x), bfhi(q0.x), bflo(q0.y), bfhi(q0.y));
        b1 = make_float4(bflo(q0.z), bfhi(q0.z), bflo(q0.w), bfhi(q0.w));
    } else {
        const float* e0 = ((row < user) ? u + (size_t)row * D
                                        : it + (size_t)(row - user) * D) + l * 8;
        b0 = *(const float4*)e0;
        b1 = *(const float4*)(e0 + 4);
    }
    uint4 q1 = *(const uint4*)(e1q + off);
    uint4 q2 = *(const uint4*)(e2q + off);
    float4 r0, r1;
    r0.x = a0 + b0.x + bflo(q1.x) + bflo(q2.x);
    r0.y = a1 + b0.y + bfhi(q1.x) + bfhi(q2.x);
    r0.z = a2 + b0.z + bflo(q1.y) + bflo(q2.y);
    r0.w = a3 + b0.w + bfhi(q1.y) + bfhi(q2.y);
    r1.x = a4 + b1.x + bflo(q1.z) + bflo(q2.z);
    r1.y = a5 + b1.y + bfhi(q1.z) + bfhi(q2.z);
    r1.z = a6 + b1.z + bflo(q1.w) + bflo(q2.w);
    r1.w = a7 + b1.w + bfhi(q1.w) + bfhi(q2.w);
    *(float4*)(acc + off) = r0;
    *(float4*)(acc + off + 4) = r1;
}

// ---------- launch ----------
static inline size_t alignup(size_t x) { return (x + 255) & ~(size_t)255; }

extern "C" void kernel_launch(void* const* d_in, const int* in_sizes, int n_in,
                              void* d_out, int out_size, void* d_ws, size_t ws_size,
                              hipStream_t stream) {
    const int*   rows = (const int*)  d_in[0];
    const int*   cols = (const int*)  d_in[1];
    const float* vals = (const float*)d_in[2];
    const float* u    = (const float*)d_in[3];
    const float* it   = (const float*)d_in[4];

    const int nedges = in_sizes[0];
    const int user   = in_sizes[3] / D;
    const int item   = in_sizes[4] / D;
    const int n      = user + item;
    const int nab    = (n + AROWS - 1) >> AB_SHIFT;   // 586

    float* acc = (float*)d_out;

    // workspace carve
    char* w0 = (char*)d_ws;
    char* w = w0;
    int*  cnt  = (int*)w;  w += alignup((size_t)nab * sizeof(int));
    int*  bptr = (int*)w;  w += alignup((size_t)(nab + 1) * sizeof(int));
    int*  gcur = (int*)w;  w += alignup((size_t)nab * sizeof(int));
    int*  endp = (int*)w;  w += alignup((size_t)n * sizeof(int));
    int2* pairs = (int2*)w; w += alignup((size_t)nedges * sizeof(int2));
    // region X: staged (E*8B, dead after bucket_sort) then e1q (n*D*2B)
    char* regX = w;         w += alignup((size_t)nedges * sizeof(int2));
    // region Y: e2q (n*D*2B)
    char* regY = w;         w += alignup((size_t)n * D * 2);
    // region Z (optional): persistent e0q (n*D*2B)
    char* regZ = w;         w += alignup((size_t)n * D * 2);
    const bool sep_e0 = ((size_t)(w - w0) <= ws_size);

    int2* staged = (int2*)regX;
    unsigned short* e1q = (unsigned short*)regX;
    unsigned short* e2q = (unsigned short*)regY;
    unsigned short* e0q = sep_e0 ? (unsigned short*)regZ
                                 : (unsigned short*)regY;  // aliased: dead after pass 1

    const int hblocks = (nedges + HEPB - 1) / HEPB;
    const int pblocks = (nedges + P_EPB - 1) / P_EPB;
    const int sblocks = (n + 31) / 32;
    const long long userD = (long long)user * D;
    const long long totalD = (long long)n * D;

    hipMemsetAsync(cnt, 0, (size_t)nab * sizeof(int), stream);
    hist_conv<<<hblocks, 256, 0, stream>>>(rows, cnt, nedges, nab,
                                           u, it, e0q, userD, totalD);
    scan_buckets<<<1, 1024, 0, stream>>>(cnt, bptr, gcur, nab, nedges);
    partition_edges<<<pblocks, P_T, 0, stream>>>(rows, cols, vals, gcur, staged, nedges, nab);
    bucket_sort<<<nab, SORT_T, 0, stream>>>(bptr, staged, pairs, endp, n);

    // pass 1: e1q = bf16(A.e0)
    spmm_mid<<<sblocks, 256, 0, stream>>>(endp, pairs, e0q, e1q, n);
    // pass 2: e2q = bf16(A.e1)
    spmm_mid<<<sblocks, 256, 0, stream>>>(endp, pairs, e1q, e2q, n);
    // pass 3: acc = e0 + e1 + e2 + A.e2
    spmm_final<<<sblocks, 256, 0, stream>>>(
        endp, pairs, e2q, e1q, sep_e0 ? e0q : nullptr, u, it, user, acc, n);
}

// Round 11
// 446.733 us; speedup vs baseline: 11.6557x; 1.0533x over previous
//
#include <hip/hip_runtime.h>

#define D 64
#define AB_SHIFT 9
#define AROWS 512                 // rows per bucket
#define NAB_MAX 640               // >= 586 buckets
#define CHP 3                     // ceil(NAB_MAX/256) bucket-chunks per thread
#define HEPB 4096                 // edges per hist block
#define P_EPB 4096                // edges per partition block
#define P_T 256
#define P_PER (P_EPB / P_T)       // 16
#define SORT_T 512
#define SORT_CAP 9472             // LDS record capacity (37 KB as u32)
#define VSCALE 8192.0f
#define VINV   (1.0f / 8192.0f)

__device__ __forceinline__ unsigned short f2bf(float f) {
    unsigned u = __float_as_uint(f);
    return (unsigned short)((u + 0x7FFFu + ((u >> 16) & 1u)) >> 16);  // RNE
}
__device__ __forceinline__ float bflo(unsigned u) {
    return __uint_as_float(u << 16);
}
__device__ __forceinline__ float bfhi(unsigned u) {
    return __uint_as_float(u & 0xFFFF0000u);
}

// ---------- fused: bucket histogram + fp32->bf16 table convert ----------
__global__ __launch_bounds__(256) void hist_conv(
    const int* __restrict__ rows, int* __restrict__ cnt, int nedges, int nab,
    const float* __restrict__ u, const float* __restrict__ it,
    unsigned short* __restrict__ q, long long userD, long long totalD)
{
    __shared__ int h[NAB_MAX];
    int t = threadIdx.x;
    for (int i = t; i < nab; i += 256) h[i] = 0;
    __syncthreads();
    int base = blockIdx.x * HEPB;
    #pragma unroll
    for (int i = 0; i < HEPB / 256; i++) {
        int e = base + i * 256 + t;
        if (e < nedges) atomicAdd(&h[rows[e] >> AB_SHIFT], 1);
    }
    __syncthreads();
    for (int i = t; i < nab; i += 256) if (h[i]) atomicAdd(&cnt[i], h[i]);
    // convert phase (independent of hist)
    long long stride = (long long)gridDim.x * 256 * 4;
    for (long long i = ((long long)blockIdx.x * 256 + t) * 4; i < totalD; i += stride) {
        float4 x = (i < userD) ? *(const float4*)(u + i)
                               : *(const float4*)(it + (i - userD));
        ushort4 o;
        o.x = f2bf(x.x); o.y = f2bf(x.y); o.z = f2bf(x.z); o.w = f2bf(x.w);
        *(ushort4*)(q + i) = o;
    }
}

// ---------- exclusive scan of bucket counts (single block) ----------
__global__ __launch_bounds__(1024) void scan_buckets(
    const int* __restrict__ cnt, int* __restrict__ bptr, int* __restrict__ gcur,
    int nab, int nedges)
{
    __shared__ int lds[1024];
    int t = threadIdx.x;
    int i0 = 2 * t, i1 = 2 * t + 1;
    int a = (i0 < nab) ? cnt[i0] : 0;
    int b = (i1 < nab) ? cnt[i1] : 0;
    int s = a + b;
    lds[t] = s;
    __syncthreads();
    for (int ofs = 1; ofs < 1024; ofs <<= 1) {
        int x = (t >= ofs) ? lds[t - ofs] : 0;
        __syncthreads();
        lds[t] += x;
        __syncthreads();
    }
    int excl = lds[t] - s;
    if (i0 < nab) { bptr[i0] = excl;     gcur[i0] = excl; }
    if (i1 < nab) { bptr[i1] = excl + a; gcur[i1] = excl + a; }
    if (t == 0) bptr[nab] = nedges;
}

// ---------- partition v2: LDS-reordered multi-split ----------
__global__ __launch_bounds__(P_T) void partition_edges(
    const int* __restrict__ rows, const int* __restrict__ cols,
    const float* __restrict__ vals, int* __restrict__ gcur,
    int2* __restrict__ staged, int nedges, int nab)
{
    __shared__ int h[NAB_MAX];        // counts -> delta (gbase - lofs)
    __shared__ int lofs[NAB_MAX];
    __shared__ int partial[P_T];
    __shared__ int mcount;
    __shared__ int2 sbuf[P_EPB];      // 32 KB
    __shared__ unsigned short bid[P_EPB]; // 8 KB
    int t = threadIdx.x;
    int base = blockIdx.x * P_EPB;
    for (int i = t; i < nab; i += P_T) h[i] = 0;
    __syncthreads();
    int pk[P_PER];
    #pragma unroll
    for (int i = 0; i < P_PER; i++) {
        int e = base + i * P_T + t;
        if (e < nedges) {
            int r = rows[e];
            int b = r >> AB_SHIFT;
            int rank = atomicAdd(&h[b], 1);
            pk[i] = (rank << 19) | ((r & (AROWS - 1)) << 10) | b;
        } else pk[i] = -1;
    }
    __syncthreads();
    int s = 0;
    int b0 = t * CHP;
    #pragma unroll
    for (int j = 0; j < CHP; j++) { int b = b0 + j; if (b < nab) s += h[b]; }
    partial[t] = s;
    __syncthreads();
    for (int ofs = 1; ofs < P_T; ofs <<= 1) {
        int x = (t >= ofs) ? partial[t - ofs] : 0;
        __syncthreads();
        partial[t] += x;
        __syncthreads();
    }
    if (t == P_T - 1) mcount = partial[t];
    int run = partial[t] - s;
    #pragma unroll
    for (int j = 0; j < CHP; j++) {
        int b = b0 + j;
        if (b < nab) { lofs[b] = run; run += h[b]; }
    }
    __syncthreads();
    for (int i = t; i < nab; i += P_T) {
        int c = h[i];
        if (c) { int gb = atomicAdd(&gcur[i], c); h[i] = gb - lofs[i]; }
    }
    __syncthreads();
    #pragma unroll
    for (int i = 0; i < P_PER; i++) {
        if (pk[i] < 0) continue;
        int e = base + i * P_T + t;
        int b = pk[i] & 1023;
        int rl = (pk[i] >> 10) & (AROWS - 1);
        int rank = (unsigned)pk[i] >> 19;
        int q = lofs[b] + rank;
        sbuf[q] = make_int2((rl << 19) | cols[e], __float_as_int(vals[e]));
        bid[q] = (unsigned short)b;
    }
    __syncthreads();
    int m = mcount;
    for (int q = t; q < m; q += P_T) {
        int b = bid[q];
        staged[h[b] + q] = sbuf[q];
    }
}

// ---------- in-LDS row sort + 4B-record pack of each bucket segment ----------
// rec = (val13 << 19) | col
__global__ __launch_bounds__(SORT_T) void bucket_sort(
    const int* __restrict__ bptr, const int2* __restrict__ staged,
    unsigned* __restrict__ pairs, int* __restrict__ endp, int n)
{
    __shared__ int cnt[AROWS];
    __shared__ int pfx[AROWS];
    __shared__ unsigned buf[SORT_CAP];   // 37 KB
    int t = threadIdx.x;
    int b = blockIdx.x;
    int seg0 = bptr[b], seg1 = bptr[b + 1];
    int len = seg1 - seg0;
    cnt[t] = 0;
    __syncthreads();
    for (int i = t; i < len; i += SORT_T) {
        int rl = (unsigned)staged[seg0 + i].x >> 19;
        atomicAdd(&cnt[rl], 1);
    }
    __syncthreads();
    pfx[t] = cnt[t];
    __syncthreads();
    for (int ofs = 1; ofs < AROWS; ofs <<= 1) {
        int x = (t >= ofs) ? pfx[t - ofs] : 0;
        __syncthreads();
        pfx[t] += x;       // inclusive prefix
        __syncthreads();
    }
    int rowbase = b << AB_SHIFT;
    if (rowbase + t < n) endp[rowbase + t] = seg0 + pfx[t];
    cnt[t] = pfx[t] - cnt[t];   // running cursor (exclusive)
    __syncthreads();
    for (int i = t; i < len; i += SORT_T) {
        int2 p = staged[seg0 + i];
        int rl = (unsigned)p.x >> 19;
        int pos = atomicAdd(&cnt[rl], 1);
        float val = __int_as_float(p.y);
        unsigned q = (unsigned)fminf(val * VSCALE + 0.5f, 8191.0f);
        unsigned rec = (q << 19) | ((unsigned)p.x & 0x7FFFF);
        if (pos < SORT_CAP) buf[pos] = rec;
        else pairs[seg0 + pos] = rec;
    }
    __syncthreads();
    int m = len < SORT_CAP ? len : SORT_CAP;
    for (int i = t; i < m; i += SORT_T) pairs[seg0 + i] = buf[i];
}

// ---------- gather core: r = A(row) . tab, 8 lanes/row, 4-deep ----------
__device__ __forceinline__ void gather_row(
    const int* __restrict__ endp, const unsigned* __restrict__ pairs,
    const uint4* __restrict__ tb, int row, int l,
    float& a0, float& a1, float& a2, float& a3,
    float& a4, float& a5, float& a6, float& a7)
{
    int start = row ? endp[row - 1] : 0;
    int end = endp[row];
    int e = start;
    for (; e + 4 <= end; e += 4) {
        unsigned p0 = pairs[e], p1 = pairs[e + 1], p2 = pairs[e + 2], p3 = pairs[e + 3];
        uint4 q0 = tb[(size_t)(p0 & 0x7FFFF) * 8 + l];
        uint4 q1 = tb[(size_t)(p1 & 0x7FFFF) * 8 + l];
        uint4 q2 = tb[(size_t)(p2 & 0x7FFFF) * 8 + l];
        uint4 q3 = tb[(size_t)(p3 & 0x7FFFF) * 8 + l];
        float v0 = (float)(p0 >> 19) * VINV;
        float v1 = (float)(p1 >> 19) * VINV;
        float v2 = (float)(p2 >> 19) * VINV;
        float v3 = (float)(p3 >> 19) * VINV;
        a0 = fmaf(v0, bflo(q0.x), a0); a1 = fmaf(v0, bfhi(q0.x), a1);
        a2 = fmaf(v0, bflo(q0.y), a2); a3 = fmaf(v0, bfhi(q0.y), a3);
        a4 = fmaf(v0, bflo(q0.z), a4); a5 = fmaf(v0, bfhi(q0.z), a5);
        a6 = fmaf(v0, bflo(q0.w), a6); a7 = fmaf(v0, bfhi(q0.w), a7);
        a0 = fmaf(v1, bflo(q1.x), a0); a1 = fmaf(v1, bfhi(q1.x), a1);
        a2 = fmaf(v1, bflo(q1.y), a2); a3 = fmaf(v1, bfhi(q1.y), a3);
        a4 = fmaf(v1, bflo(q1.z), a4); a5 = fmaf(v1, bfhi(q1.z), a5);
        a6 = fmaf(v1, bflo(q1.w), a6); a7 = fmaf(v1, bfhi(q1.w), a7);
        a0 = fmaf(v2, bflo(q2.x), a0); a1 = fmaf(v2, bfhi(q2.x), a1);
        a2 = fmaf(v2, bflo(q2.y), a2); a3 = fmaf(v2, bfhi(q2.y), a3);
        a4 = fmaf(v2, bflo(q2.z), a4); a5 = fmaf(v2, bfhi(q2.z), a5);
        a6 = fmaf(v2, bflo(q2.w), a6); a7 = fmaf(v2, bfhi(q2.w), a7);
        a0 = fmaf(v3, bflo(q3.x), a0); a1 = fmaf(v3, bfhi(q3.x), a1);
        a2 = fmaf(v3, bflo(q3.y), a2); a3 = fmaf(v3, bfhi(q3.y), a3);
        a4 = fmaf(v3, bflo(q3.z), a4); a5 = fmaf(v3, bfhi(q3.z), a5);
        a6 = fmaf(v3, bflo(q3.w), a6); a7 = fmaf(v3, bfhi(q3.w), a7);
    }
    for (; e < end; ++e) {
        unsigned p = pairs[e];
        uint4 q0 = tb[(size_t)(p & 0x7FFFF) * 8 + l];
        float v = (float)(p >> 19) * VINV;
        a0 = fmaf(v, bflo(q0.x), a0); a1 = fmaf(v, bfhi(q0.x), a1);
        a2 = fmaf(v, bflo(q0.y), a2); a3 = fmaf(v, bfhi(q0.y), a3);
        a4 = fmaf(v, bflo(q0.z), a4); a5 = fmaf(v, bfhi(q0.z), a5);
        a6 = fmaf(v, bflo(q0.w), a6); a7 = fmaf(v, bfhi(q0.w), a7);
    }
}

// ---------- mid pass: outq = bf16(A . tab), no acc traffic ----------
__global__ __launch_bounds__(256) void spmm_mid(
    const int* __restrict__ endp, const unsigned* __restrict__ pairs,
    const unsigned short* __restrict__ tab,
    unsigned short* __restrict__ outq, int n)
{
    int row = blockIdx.x * 32 + (threadIdx.x >> 3);
    if (row >= n) return;
    int l = threadIdx.x & 7;
    float a0=0.f,a1=0.f,a2=0.f,a3=0.f,a4=0.f,a5=0.f,a6=0.f,a7=0.f;
    gather_row(endp, pairs, (const uint4*)tab, row, l, a0,a1,a2,a3,a4,a5,a6,a7);
    uint4 o;
    o.x = ((unsigned)f2bf(a1) << 16) | f2bf(a0);
    o.y = ((unsigned)f2bf(a3) << 16) | f2bf(a2);
    o.z = ((unsigned)f2bf(a5) << 16) | f2bf(a4);
    o.w = ((unsigned)f2bf(a7) << 16) | f2bf(a6);
    *(uint4*)(outq + (size_t)row * D + l * 8) = o;
}

// ---------- final pass: acc = e0 + e1q + e2q + A . e2q ----------
__global__ __launch_bounds__(256) void spmm_final(
    const int* __restrict__ endp, const unsigned* __restrict__ pairs,
    const unsigned short* __restrict__ e2q, const unsigned short* __restrict__ e1q,
    const unsigned short* __restrict__ e0q,
    const float* __restrict__ u, const float* __restrict__ it, int user,
    float* __restrict__ acc, int n)
{
    int row = blockIdx.x * 32 + (threadIdx.x >> 3);
    if (row >= n) return;
    int l = threadIdx.x & 7;
    float a0=0.f,a1=0.f,a2=0.f,a3=0.f,a4=0.f,a5=0.f,a6=0.f,a7=0.f;
    gather_row(endp, pairs, (const uint4*)e2q, row, l, a0,a1,a2,a3,a4,a5,a6,a7);
    size_t off = (size_t)row * D + l * 8;
    float4 b0, b1;
    if (e0q) {
        uint4 q0 = *(const uint4*)(e0q + off);
        b0 = make_float4(bflo(q0.x), bfhi(q0.x), bflo(q0.y), bfhi(q0.y));
        b1 = make_float4(bflo(q0.z), bfhi(q0.z), bflo(q0.w), bfhi(q0.w));
    } else {
        const float* e0 = ((row < user) ? u + (size_t)row * D
                                        : it + (size_t)(row - user) * D) + l * 8;
        b0 = *(const float4*)e0;
        b1 = *(const float4*)(e0 + 4);
    }
    uint4 q1 = *(const uint4*)(e1q + off);
    uint4 q2 = *(const uint4*)(e2q + off);
    float4 r0, r1;
    r0.x = a0 + b0.x + bflo(q1.x) + bflo(q2.x);
    r0.y = a1 + b0.y + bfhi(q1.x) + bfhi(q2.x);
    r0.z = a2 + b0.z + bflo(q1.y) + bflo(q2.y);
    r0.w = a3 + b0.w + bfhi(q1.y) + bfhi(q2.y);
    r1.x = a4 + b1.x + bflo(q1.z) + bflo(q2.z);
    r1.y = a5 + b1.y + bfhi(q1.z) + bfhi(q2.z);
    r1.z = a6 + b1.z + bflo(q1.w) + bflo(q2.w);
    r1.w = a7 + b1.w + bfhi(q1.w) + bfhi(q2.w);
    *(float4*)(acc + off) = r0;
    *(float4*)(acc + off + 4) = r1;
}

// ---------- launch ----------
static inline size_t alignup(size_t x) { return (x + 255) & ~(size_t)255; }

extern "C" void kernel_launch(void* const* d_in, const int* in_sizes, int n_in,
                              void* d_out, int out_size, void* d_ws, size_t ws_size,
                              hipStream_t stream) {
    const int*   rows = (const int*)  d_in[0];
    const int*   cols = (const int*)  d_in[1];
    const float* vals = (const float*)d_in[2];
    const float* u    = (const float*)d_in[3];
    const float* it   = (const float*)d_in[4];

    const int nedges = in_sizes[0];
    const int user   = in_sizes[3] / D;
    const int item   = in_sizes[4] / D;
    const int n      = user + item;
    const int nab    = (n + AROWS - 1) >> AB_SHIFT;   // 586

    float* acc = (float*)d_out;

    // workspace carve
    char* w0 = (char*)d_ws;
    char* w = w0;
    int*  cnt  = (int*)w;  w += alignup((size_t)nab * sizeof(int));
    int*  bptr = (int*)w;  w += alignup((size_t)(nab + 1) * sizeof(int));
    int*  gcur = (int*)w;  w += alignup((size_t)nab * sizeof(int));
    int*  endp = (int*)w;  w += alignup((size_t)n * sizeof(int));
    unsigned* pairs = (unsigned*)w; w += alignup((size_t)nedges * sizeof(unsigned));
    // region X: staged (E*8B, dead after bucket_sort) then e1q (n*D*2B)
    char* regX = w;         w += alignup((size_t)nedges * sizeof(int2));
    // region Y: e2q (n*D*2B)
    char* regY = w;         w += alignup((size_t)n * D * 2);
    // region Z (optional): persistent e0q (n*D*2B)
    char* regZ = w;         w += alignup((size_t)n * D * 2);
    const bool sep_e0 = ((size_t)(w - w0) <= ws_size);

    int2* staged = (int2*)regX;
    unsigned short* e1q = (unsigned short*)regX;
    unsigned short* e2q = (unsigned short*)regY;
    unsigned short* e0q = sep_e0 ? (unsigned short*)regZ
                                 : (unsigned short*)regY;  // aliased: dead after pass 1

    const int hblocks = (nedges + HEPB - 1) / HEPB;
    const int pblocks = (nedges + P_EPB - 1) / P_EPB;
    const int sblocks = (n + 31) / 32;
    const long long userD = (long long)user * D;
    const long long totalD = (long long)n * D;

    hipMemsetAsync(cnt, 0, (size_t)nab * sizeof(int), stream);
    hist_conv<<<hblocks, 256, 0, stream>>>(rows, cnt, nedges, nab,
                                           u, it, e0q, userD, totalD);
    scan_buckets<<<1, 1024, 0, stream>>>(cnt, bptr, gcur, nab, nedges);
    partition_edges<<<pblocks, P_T, 0, stream>>>(rows, cols, vals, gcur, staged, nedges, nab);
    bucket_sort<<<nab, SORT_T, 0, stream>>>(bptr, staged, pairs, endp, n);

    // pass 1: e1q = bf16(A.e0)
    spmm_mid<<<sblocks, 256, 0, stream>>>(endp, pairs, e0q, e1q, n);
    // pass 2: e2q = bf16(A.e1)
    spmm_mid<<<sblocks, 256, 0, stream>>>(endp, pairs, e1q, e2q, n);
    // pass 3: acc = e0 + e1 + e2 + A.e2
    spmm_final<<<sblocks, 256, 0, stream>>>(
        endp, pairs, e2q, e1q, sep_e0 ? e0q : nullptr, u, it, user, acc, n);
}